// Round 12
// baseline (567.334 us; speedup 1.0000x reference)
//
#include <hip/hip_runtime.h>
#include <stdint.h>

#define HIDDEN  2560
#define NHEADS  32
#define HEAD    80
#define QKS     96           // Q/K padded head stride (3 x 32 for MFMA K)
#define SEQ     2048
#define BATCH   2
#define M_TOTAL (BATCH*SEQ)  // 4096
#define QKV_N   (3*HIDDEN)   // 7680
#define PART_SLOTS 36

typedef __attribute__((ext_vector_type(8))) short  short8;
typedef __attribute__((ext_vector_type(4))) float  floatx4;
typedef __attribute__((ext_vector_type(4))) float  fvec4;
typedef __attribute__((ext_vector_type(4))) unsigned short usvec4;
typedef __attribute__((ext_vector_type(2))) unsigned int uint2v;

#define SBAR() __builtin_amdgcn_sched_barrier(0)

__device__ __forceinline__ unsigned short f2bf(float x){
  union { float f; unsigned u; } v; v.f = x;
  unsigned r = v.u + 0x7fffu + ((v.u >> 16) & 1u);
  return (unsigned short)(r >> 16);
}
__device__ __forceinline__ float bf2f(unsigned short h){
  union { unsigned u; float f; } v; v.u = ((unsigned)h) << 16;
  return v.f;
}
__device__ __forceinline__ unsigned cvt_pk_bf16(float lo, float hi){
  unsigned r;
  asm volatile("v_cvt_pk_bf16_f32 %0, %1, %2" : "=v"(r) : "v"(lo), "v"(hi));
  return r;
}
__device__ __forceinline__ void gload16(const void* g, void* l){
  __builtin_amdgcn_global_load_lds(
    (const __attribute__((address_space(1))) void*)g,
    (__attribute__((address_space(3))) void*)l, 16, 0, 0);
}

// ---------------- f32 -> bf16 convert ----------------
__global__ __launch_bounds__(256)
void convert_f32_bf16(const float* __restrict__ src, unsigned short* __restrict__ dst, int n4){
  int idx = blockIdx.x*blockDim.x + threadIdx.x;
  int stride = gridDim.x*blockDim.x;
  for (int i = idx; i < n4; i += stride){
    fvec4 v = *(const fvec4*)(src + (size_t)i*4);
    usvec4 o;
    o[0]=f2bf(v[0]); o[1]=f2bf(v[1]); o[2]=f2bf(v[2]); o[3]=f2bf(v[3]);
    *(usvec4*)(dst + (size_t)i*4) = o;
  }
}

// ---------------- 256x256 GEMM, m201-style 4-phase/K-tile pipeline --------
// C[M,N] = A[M,K] * B[N,K]^T + bias. 512 threads = 8 waves (2M x 4N),
// per-wave 128x64. BK=64; LDS = 2buf x {A,B} x {kk0,kk1} slots of [256][32].
// Phase = {ds_read quadrant; issue 1 stage unit (2 gloads); barrier;
// 16 MFMA (setprio); barrier}. Stage cursor 6 units ahead; vmcnt(4) once
// per K-tile (ph3), vmcnt(0) only at tile nt-2. Slot writes provably
// race-free: target slot's last reader finished >=1 barrier earlier.
template<bool OUT_BF16>
__global__ __launch_bounds__(512, 2)
void gemm256(const unsigned short* __restrict__ A, const unsigned short* __restrict__ Bm,
             const float* __restrict__ bias, void* __restrict__ Cout,
             int M, int N, int K)
{
  __shared__ __align__(16) unsigned short lds[65536];   // 128 KB
  const int tid  = threadIdx.x;
  const int lane = tid & 63;
  const int w    = tid >> 6;          // wave 0..7
  const int wm   = w >> 2;            // 0..1
  const int wn   = w & 3;             // 0..3
  const int l15  = lane & 15, lg = lane >> 4;

  // XCD-aware tile swizzle (grid blocks %8 == 0)
  const int gx  = gridDim.x;
  const int lid = blockIdx.y*gx + blockIdx.x;
  const int nwg = gx*gridDim.y;
  const int qch = nwg >> 3;
  const int sl  = (lid & 7)*qch + (lid >> 3);
  const int bn0 = (sl % gx) * 256;
  const int bm0 = (sl / gx) * 256;

  const int nt = K >> 6;              // K-tiles of 64
  const int NU = nt*4;                // stage units (2 gloads each)

  // stage geometry: unit covers one [256][32] slot = 1024 16B-chunks;
  // instr (w,q) covers chunks (w*2+q)*64 + lane. chunk = row*4 + ((c+(row>>1))&3)
  int rowq[2], cq[2];
  #pragma unroll
  for (int q=0;q<2;q++){
    int u = (w*2+q)*64 + lane;
    rowq[q] = u >> 2;
    cq[q]   = ((u & 3) - (rowq[q] >> 1)) & 3;
  }
  const int rot = (lg + (l15 >> 1)) & 3;   // read-side chunk rotation

  floatx4 acc[8][4];
  #pragma unroll
  for (int m=0;m<8;m++)
    #pragma unroll
    for (int n=0;n<4;n++) acc[m][n] = (floatx4)0.0f;

  // unit u: tau = u>>2; j = u&3: mat = j&1 (0=A,1=B), kkh = j>>1
  auto STAGE_UNIT = [&](int u){
    const int tau = u >> 2, j = u & 3;
    const int mat = j & 1;
    const int kkh = j >> 1;
    const unsigned base = (unsigned)(((((tau & 1)*2 + mat)*2) + kkh) * 8192);
    const unsigned short* src = mat ? Bm : A;
    const int r0 = mat ? bn0 : bm0;
    const size_t kofs = (size_t)tau*64 + kkh*32;
    #pragma unroll
    for (int q=0;q<2;q++)
      gload16(src + (size_t)(r0 + rowq[q])*K + kofs + cq[q]*8, &lds[base + (w*2+q)*512]);
  };

  short8 af[4], bfv[4];
  auto READ_B = [&](int bufb, int kkh){
    const unsigned short* Bs = &lds[((bufb*2+1)*2+kkh)*8192];
    #pragma unroll
    for (int n=0;n<4;n++)
      bfv[n] = *(const short8*)&Bs[(((wn*64 + n*16 + l15)<<2) + rot)*8];
  };
  auto READ_A = [&](int bufb, int kkh, int mh){
    const unsigned short* As = &lds[((bufb*2+0)*2+kkh)*8192];
    #pragma unroll
    for (int m=0;m<4;m++)
      af[m] = *(const short8*)&As[(((wm*128 + (mh*4+m)*16 + l15)<<2) + rot)*8];
  };

  // prologue: 6 units ahead (tile0 complete + tile1 kk0 pair)
  int u = 0;
  for (; u < 6 && u < NU; ++u) STAGE_UNIT(u);
  if (NU > 6) asm volatile("s_waitcnt vmcnt(4)" ::: "memory");
  else        asm volatile("s_waitcnt vmcnt(0)" ::: "memory");
  SBAR(); __builtin_amdgcn_s_barrier(); SBAR();

  for (int t=0; t<nt; ++t){
    const int c = t & 1;
    #pragma unroll
    for (int ph=0; ph<4; ++ph){
      const int kkh = ph >> 1, mh = ph & 1;
      if (mh == 0) READ_B(c, kkh);
      READ_A(c, kkh, mh);
      if (u < NU){ STAGE_UNIT(u); ++u; }
      if (ph == 3){
        if (t < nt-2)       asm volatile("s_waitcnt vmcnt(4)" ::: "memory");
        else if (t == nt-2) asm volatile("s_waitcnt vmcnt(0)" ::: "memory");
      }
      SBAR(); __builtin_amdgcn_s_barrier(); SBAR();
      __builtin_amdgcn_s_setprio(1);
      #pragma unroll
      for (int m=0;m<4;m++)
        #pragma unroll
        for (int n=0;n<4;n++)
          acc[mh*4+m][n] = __builtin_amdgcn_mfma_f32_16x16x32_bf16(af[m], bfv[n], acc[mh*4+m][n], 0, 0, 0);
      __builtin_amdgcn_s_setprio(0);
      SBAR(); __builtin_amdgcn_s_barrier(); SBAR();
    }
  }

  // epilogue
  #pragma unroll
  for (int m=0;m<8;m++){
    #pragma unroll
    for (int n=0;n<4;n++){
      int col = bn0 + wn*64 + n*16 + l15;
      float bs = bias[col];
      #pragma unroll
      for (int r=0;r<4;r++){
        int row = bm0 + wm*128 + m*16 + lg*4 + r;
        float v = acc[m][n][r] + bs;
        if (OUT_BF16) ((unsigned short*)Cout)[(size_t)row*N + col] = f2bf(v);
        else          ((float*)Cout)[(size_t)row*N + col] = v;
      }
    }
  }
}

// ---------------- RoPE + scatter to attention layouts ----------------
// qkv [B,S,7680] bf16 -> Qp,Kp [B,H,S,96] (rope d<32, zero d>=80), Vt [B,H,80,S]
__global__ __launch_bounds__(256)
void rope_scatter(const unsigned short* __restrict__ qkv,
                  const int* __restrict__ pos_ids,
                  unsigned short* __restrict__ Qp, unsigned short* __restrict__ Kp,
                  unsigned short* __restrict__ Vt)
{
  __shared__ float cosb[128*16];
  __shared__ float sinb[128*16];
  __shared__ __align__(16) unsigned short vtile[128*88];
  const int tid = threadIdx.x;
  const int blk = blockIdx.x;
  const int st = blk & 15, h = (blk >> 4) & 31, b = blk >> 9;
  const int s0 = st*128;

  for (int idx = tid; idx < 128*16; idx += 256){
    int sl = idx >> 4, i = idx & 15;
    float p = (float)pos_ids[b*SEQ + s0 + sl];
    float inv = exp2f(-(float)i * (13.287712379549449f/16.0f));
    float ang = p * inv;
    cosb[idx] = cosf(ang);
    sinb[idx] = sinf(ang);
  }
  __syncthreads();

  const size_t qkrow = (size_t)(b*SEQ + s0)*QKV_N;
  const size_t obase = ((size_t)(b*NHEADS + h)*SEQ + s0)*QKS;
  #pragma unroll
  for (int part = 0; part < 2; part++){
    const int cbase = part*HIDDEN + h*HEAD;
    unsigned short* outp = part ? Kp : Qp;
    for (int idx = tid; idx < 128*QKS; idx += 256){
      int sl = idx / QKS, d = idx - sl*QKS;
      const size_t rb = qkrow + (size_t)sl*QKV_N + cbase;
      float v;
      if (d < 16){
        float x1 = bf2f(qkv[rb + d]);
        float x2 = bf2f(qkv[rb + d + 16]);
        v = x1*cosb[sl*16 + d] - x2*sinb[sl*16 + d];
      } else if (d < 32){
        int i = d - 16;
        float x1 = bf2f(qkv[rb + d - 16]);
        float x2 = bf2f(qkv[rb + d]);
        v = x2*cosb[sl*16 + i] + x1*sinb[sl*16 + i];
      } else if (d < HEAD){
        v = bf2f(qkv[rb + d]);
      } else v = 0.0f;
      outp[obase + (size_t)sl*QKS + d] = f2bf(v);
    }
  }

  for (int idx = tid; idx < 128*HEAD; idx += 256){
    int sl = idx / HEAD, d = idx - sl*HEAD;
    vtile[sl*88 + d] = qkv[qkrow + (size_t)sl*QKV_N + 2*HIDDEN + h*HEAD + d];
  }
  __syncthreads();
  const size_t vtb = ((size_t)(b*NHEADS + h)*HEAD)*SEQ + s0;
  for (int idx = tid; idx < HEAD*128; idx += 256){
    int d = idx >> 7, sl = idx & 127;
    Vt[vtb + (size_t)d*SEQ + sl] = vtile[sl*88 + d];
  }
}

// ---------------- flash attention (causal, kv-split, LDS-shared tiles) ----
__global__ __launch_bounds__(256, 4)
void attn_fd(const unsigned short* __restrict__ Qp,
             const unsigned short* __restrict__ Kp,
             const unsigned short* __restrict__ Vt,
             unsigned short* __restrict__ ctx,
             unsigned short* __restrict__ pO,
             float* __restrict__ pML)
{
  __shared__ __align__(16) unsigned short Klds[64*96];    // 12 KB, swizzled
  __shared__ __align__(16) unsigned short Vlds[80*64];    // 10 KB, swizzled
  __shared__ __align__(16) unsigned short p_lds[4][32*36];// 9.2 KB, kk-halves
  const int tid = threadIdx.x;
  const int lane = tid & 63, w = tid >> 6;
  const int l15 = lane & 15, lg = lane >> 4;

  const int bid = blockIdx.x;
  const int xcd = bid & 7, j = bid >> 3;     // j 0..319
  const int bh  = (j/40)*8 + xcd;
  const int tr  = j - (j/40)*40;

  int qt, part, np;
  if (tr < 16)      { qt = 12 + (tr>>2); part = tr & 3; np = 4; }
  else if (tr < 28) { int t = tr-16; int q3 = t/3; qt = 8 + q3; part = t - q3*3; np = 3; }
  else if (tr < 36) { int t = tr-28; qt = 4 + (t>>1); part = t & 1; np = 2; }
  else              { qt = tr - 36; part = 0; np = 1; }
  const int nk  = 2*qt + 2;
  const int kt0 = (part*nk)/np, kt1 = ((part+1)*nk)/np;
  const int q0  = qt*128 + w*32;

  const unsigned short* Qb = Qp + ((size_t)bh*SEQ)*QKS;
  const unsigned short* Kb = Kp + ((size_t)bh*SEQ)*QKS;
  const unsigned short* Vb = Vt + ((size_t)bh*HEAD)*SEQ;

  short8 qf[2][3];
  #pragma unroll
  for (int mi=0; mi<2; mi++)
    #pragma unroll
    for (int kc=0; kc<3; kc++)
      qf[mi][kc] = *(const short8*)&Qb[(size_t)(q0 + mi*16 + l15)*QKS + kc*32 + lg*8];

  int ksrow[3], ksc[3];
  #pragma unroll
  for (int t=0;t<3;t++){
    int ci = (w*3 + t)*64 + lane;       // K chunk 0..767
    int row = ci/12, c = ci - row*12;
    ksrow[t] = row;
    ksc[t]   = (c ^ (row & 3))*8;
  }
  int vsrow[3], vsc[3];
  #pragma unroll
  for (int t=0;t<3;t++){
    int i = w + 4*t;                    // V instr 0..9
    int row = i*8 + (lane >> 3), c = lane & 7;
    vsrow[t] = row;
    vsc[t]   = (c ^ (row & 7))*8;
  }

  float mrun[2] = {-3e38f, -3e38f};
  float lrun[2] = {0.0f, 0.0f};
  floatx4 oacc[2][5];
  #pragma unroll
  for (int mi=0;mi<2;mi++)
    #pragma unroll
    for (int di=0;di<5;di++) oacc[mi][di] = (floatx4)0.0f;

  const float SC = 0.1118033988749895f * 1.4426950408889634f; // 1/sqrt(80)*log2(e)

  for (int kt = kt0; kt < kt1; kt++){
    #pragma unroll
    for (int t=0;t<3;t++)
      gload16(Kb + (size_t)(kt*64 + ksrow[t])*QKS + ksc[t], &Klds[(w*3+t)*512]);
    #pragma unroll
    for (int t=0;t<3;t++){
      int i = w + 4*t;
      if (i < 10)
        gload16(Vb + (size_t)vsrow[t]*SEQ + kt*64 + vsc[t], &Vlds[i*512]);
    }
    __syncthreads();

    if (kt*64 <= q0 + 31){
      floatx4 sacc[2][4];
      #pragma unroll
      for (int mi=0;mi<2;mi++)
        #pragma unroll
        for (int ni=0;ni<4;ni++) sacc[mi][ni] = (floatx4)0.0f;

      __builtin_amdgcn_s_setprio(1);
      #pragma unroll
      for (int kc=0; kc<3; kc++){
        short8 kf[4];
        #pragma unroll
        for (int ni=0; ni<4; ni++){
          int r = ni*16 + l15;
          kf[ni] = *(const short8*)&Klds[r*96 + (((kc*4+lg) ^ (r & 3))<<3)];
        }
        #pragma unroll
        for (int mi=0; mi<2; mi++)
          #pragma unroll
          for (int ni=0; ni<4; ni++)
            sacc[mi][ni] = __builtin_amdgcn_mfma_f32_16x16x32_bf16(kf[ni], qf[mi][kc], sacc[mi][ni], 0, 0, 0);
      }
      __builtin_amdgcn_s_setprio(0);

      if (kt*64 + 63 > q0){
        #pragma unroll
        for (int mi=0; mi<2; mi++){
          int qrow = q0 + mi*16 + l15;
          #pragma unroll
          for (int ni=0; ni<4; ni++){
            int kb = kt*64 + ni*16 + lg*4;
            #pragma unroll
            for (int r=0; r<4; r++)
              if (kb + r > qrow) sacc[mi][ni][r] = -3e38f;
          }
        }
      }

      #pragma unroll
      for (int mi=0; mi<2; mi++){
        float pm = -3e38f;
        #pragma unroll
        for (int ni=0; ni<4; ni++)
          #pragma unroll
          for (int r=0; r<4; r++) pm = fmaxf(pm, sacc[mi][ni][r]);
        pm = fmaxf(pm, __shfl_xor(pm, 16));
        pm = fmaxf(pm, __shfl_xor(pm, 32));
        float mold = mrun[mi];
        float mnew = fmaxf(mold, pm);
        float msc  = mnew*SC;
        float alpha = __builtin_amdgcn_exp2f(mold*SC - msc);
        float rs = 0.0f;
        #pragma unroll
        for (int ni=0; ni<4; ni++)
          #pragma unroll
          for (int r=0; r<4; r++){
            float p = __builtin_amdgcn_exp2f(sacc[mi][ni][r]*SC - msc);
            sacc[mi][ni][r] = p;
            rs += p;
          }
        rs += __shfl_xor(rs, 16);
        rs += __shfl_xor(rs, 32);
        lrun[mi] = lrun[mi]*alpha + rs;
        mrun[mi] = mnew;
        #pragma unroll
        for (int di=0; di<5; di++) oacc[mi][di] *= alpha;
      }

      #pragma unroll
      for (int kk=0; kk<2; kk++){
        #pragma unroll
        for (int mi=0; mi<2; mi++)
          #pragma unroll
          for (int nl=0; nl<2; nl++){
            int ni = kk*2 + nl;
            uint2v pk;
            pk[0] = cvt_pk_bf16(sacc[mi][ni][0], sacc[mi][ni][1]);
            pk[1] = cvt_pk_bf16(sacc[mi][ni][2], sacc[mi][ni][3]);
            *(uint2v*)&p_lds[w][(mi*16 + l15)*36 + nl*16 + lg*4] = pk;
          }
        __builtin_amdgcn_s_setprio(1);
        short8 pa[2];
        #pragma unroll
        for (int mi=0;mi<2;mi++)
          pa[mi] = *(const short8*)&p_lds[w][(mi*16 + l15)*36 + lg*8];
        #pragma unroll
        for (int di=0; di<5; di++){
          int r = di*16 + l15;
          short8 vf = *(const short8*)&Vlds[r*64 + (((kk*4+lg) ^ (r & 7))<<3)];
          #pragma unroll
          for (int mi=0;mi<2;mi++)
            oacc[mi][di] = __builtin_amdgcn_mfma_f32_16x16x32_bf16(vf, pa[mi], oacc[mi][di], 0, 0, 0);
        }
        __builtin_amdgcn_s_setprio(0);
      }
    }
    __syncthreads();
  }

  const int b = bh >> 5, h = bh & 31;
  if (np == 1){
    #pragma unroll
    for (int mi=0;mi<2;mi++){
      float inv = 1.0f/lrun[mi];
      size_t crow = ((size_t)(b*SEQ + q0 + mi*16 + l15))*HIDDEN + h*HEAD;
      #pragma unroll
      for (int di=0;di<5;di++){
        uint2v pk;
        pk[0] = cvt_pk_bf16(oacc[mi][di][0]*inv, oacc[mi][di][1]*inv);
        pk[1] = cvt_pk_bf16(oacc[mi][di][2]*inv, oacc[mi][di][3]*inv);
        *(uint2v*)&ctx[crow + di*16 + lg*4] = pk;
      }
    }
  } else {
    int base;
    if (np == 2)      base = (qt-4)*2;
    else if (np == 3) base = 8 + (qt-8)*3;
    else              base = 20 + (qt-12)*4;
    const int pslot = bh*PART_SLOTS + base + part;
    unsigned short* Ob = pO + (size_t)pslot*128*HEAD;
    #pragma unroll
    for (int mi=0;mi<2;mi++){
      int grow = w*32 + mi*16 + l15;
      #pragma unroll
      for (int di=0;di<5;di++){
        uint2v pk;
        pk[0] = cvt_pk_bf16(oacc[mi][di][0], oacc[mi][di][1]);
        pk[1] = cvt_pk_bf16(oacc[mi][di][2], oacc[mi][di][3]);
        *(uint2v*)&Ob[grow*HEAD + di*16 + lg*4] = pk;
      }
      if (lg == 0){
        float* mlb = pML + ((size_t)pslot*128 + grow)*2;
        mlb[0] = mrun[mi];
        mlb[1] = lrun[mi];
      }
    }
  }
}

// ---------------- combine partials (coalesced flat-tile reads) ----------------
__global__ __launch_bounds__(256)
void attn_combine(const unsigned short* __restrict__ pO, const float* __restrict__ pML,
                  unsigned short* __restrict__ ctx)
{
  const int bid = blockIdx.x;              // 64*12
  const int bh = bid / 12, qt = 4 + (bid - (bid/12)*12);
  int base, np;
  if (qt < 8)       { base = (qt-4)*2;       np = 2; }
  else if (qt < 12) { base = 8 + (qt-8)*3;   np = 3; }
  else              { base = 20 + (qt-12)*4; np = 4; }
  const int slot0 = bh*PART_SLOTS + base;
  const float SC = 0.1118033988749895f * 1.4426950408889634f;
  const int b = bh >> 5, h = bh & 31;

  #pragma unroll
  for (int c = 0; c < 5; c++){
    const int e   = c*2048 + threadIdx.x*8;   // element in flat 128x80 tile
    const int row = e / 80, d = e - row*80;   // 80%8==0: never crosses rows

    float m[4], l[4], ms = -3e38f;
    for (int p=0;p<np;p++){
      const float* mlb = pML + ((size_t)(slot0+p)*128 + row)*2;
      m[p] = mlb[0]; l[p] = mlb[1];
      ms = fmaxf(ms, m[p]);
    }
    float wgt[4], lsum = 0.0f;
    for (int p=0;p<np;p++){
      wgt[p] = exp2f((m[p]-ms)*SC);
      lsum += wgt[p]*l[p];
    }
    const float inv = 1.0f/lsum;

    float acc[8] = {0,0,0,0,0,0,0,0};
    for (int p=0;p<np;p++){
      short8 v = *(const short8*)&pO[(size_t)(slot0+p)*128*HEAD + e];
      #pragma unroll
      for (int j=0;j<8;j++) acc[j] += wgt[p]*bf2f((unsigned short)v[j]);
    }
    short8 o;
    #pragma unroll
    for (int j=0;j<8;j++) o[j] = (short)f2bf(acc[j]*inv);
    *(short8*)&ctx[((size_t)(b*SEQ + qt*128 + row))*HIDDEN + h*HEAD + d] = o;
  }
}

// ---------------- launch ----------------
extern "C" void kernel_launch(void* const* d_in, const int* in_sizes, int n_in,
                              void* d_out, int out_size, void* d_ws, size_t ws_size,
                              hipStream_t stream)
{
  const int*   pos  = (const int*)  d_in[0];
  const float* hid  = (const float*)d_in[1];
  const float* wqkv = (const float*)d_in[2];
  const float* bqkv = (const float*)d_in[3];
  const float* outw = (const float*)d_in[4];
  const float* outb = (const float*)d_in[5];

  char* ws = (char*)d_ws;
  size_t off = 0;
  auto alloc = [&](size_t bytes)->void*{
    void* p = ws + off; off += (bytes + 255) & ~(size_t)255; return p;
  };
  unsigned short* hid_bf  = (unsigned short*)alloc((size_t)M_TOTAL*HIDDEN*2);   // reused as ctx
  unsigned short* wqkv_bf = (unsigned short*)alloc((size_t)QKV_N*HIDDEN*2);
  unsigned short* outw_bf = (unsigned short*)alloc((size_t)HIDDEN*HIDDEN*2);
  unsigned short* qkv_bf  = (unsigned short*)alloc((size_t)M_TOTAL*QKV_N*2);    // reused as partials
  unsigned short* Qp      = (unsigned short*)alloc((size_t)BATCH*NHEADS*SEQ*QKS*2);
  unsigned short* Kp      = (unsigned short*)alloc((size_t)BATCH*NHEADS*SEQ*QKS*2);
  unsigned short* Vt      = (unsigned short*)alloc((size_t)BATCH*NHEADS*HEAD*SEQ*2);
  if (off > ws_size) return;

  unsigned short* pO  = qkv_bf;                                            // 47.2 MB
  float*          pML = (float*)(qkv_bf + (size_t)64*PART_SLOTS*128*HEAD); // 2.36 MB

  convert_f32_bf16<<<dim3(1024), dim3(256), 0, stream>>>(hid,  hid_bf,  M_TOTAL*HIDDEN/4);
  convert_f32_bf16<<<dim3(2048), dim3(256), 0, stream>>>(wqkv, wqkv_bf, QKV_N*HIDDEN/4);
  convert_f32_bf16<<<dim3(1024), dim3(256), 0, stream>>>(outw, outw_bf, HIDDEN*HIDDEN/4);

  gemm256<true><<<dim3(QKV_N/256, M_TOTAL/256), dim3(512), 0, stream>>>(
      hid_bf, wqkv_bf, bqkv, (void*)qkv_bf, M_TOTAL, QKV_N, HIDDEN);

  rope_scatter<<<dim3(BATCH*NHEADS*16), dim3(256), 0, stream>>>(qkv_bf, pos, Qp, Kp, Vt);

  unsigned short* ctx = hid_bf;  // hidden_bf dead after QKV GEMM
  attn_fd<<<dim3(2560), dim3(256), 0, stream>>>(Qp, Kp, Vt, ctx, pO, pML);
  attn_combine<<<dim3(64*12), dim3(256), 0, stream>>>(pO, pML, ctx);

  gemm256<false><<<dim3(HIDDEN/256, M_TOTAL/256), dim3(512), 0, stream>>>(
      ctx, outw_bf, outb, d_out, M_TOTAL, HIDDEN, HIDDEN);
}

// Round 13
// 566.727 us; speedup vs baseline: 1.0011x; 1.0011x over previous
//
#include <hip/hip_runtime.h>
#include <stdint.h>

#define HIDDEN  2560
#define NHEADS  32
#define HEAD    80
#define QKS     96           // Q/K padded head stride (3 x 32 for MFMA K)
#define SEQ     2048
#define BATCH   2
#define M_TOTAL (BATCH*SEQ)  // 4096
#define QKV_N   (3*HIDDEN)   // 7680
#define PART_SLOTS 36

typedef __attribute__((ext_vector_type(8))) short  short8;
typedef __attribute__((ext_vector_type(4))) float  floatx4;
typedef __attribute__((ext_vector_type(4))) float  fvec4;
typedef __attribute__((ext_vector_type(4))) unsigned short usvec4;
typedef __attribute__((ext_vector_type(2))) unsigned int uint2v;

#define SBAR() __builtin_amdgcn_sched_barrier(0)

__device__ __forceinline__ unsigned short f2bf(float x){
  union { float f; unsigned u; } v; v.f = x;
  unsigned r = v.u + 0x7fffu + ((v.u >> 16) & 1u);
  return (unsigned short)(r >> 16);
}
__device__ __forceinline__ float bf2f(unsigned short h){
  union { unsigned u; float f; } v; v.u = ((unsigned)h) << 16;
  return v.f;
}
__device__ __forceinline__ unsigned cvt_pk_bf16(float lo, float hi){
  unsigned r;
  asm volatile("v_cvt_pk_bf16_f32 %0, %1, %2" : "=v"(r) : "v"(lo), "v"(hi));
  return r;
}
__device__ __forceinline__ void gload16(const void* g, void* l){
  __builtin_amdgcn_global_load_lds(
    (const __attribute__((address_space(1))) void*)g,
    (__attribute__((address_space(3))) void*)l, 16, 0, 0);
}

// ---------------- f32 -> bf16 convert ----------------
__global__ __launch_bounds__(256)
void convert_f32_bf16(const float* __restrict__ src, unsigned short* __restrict__ dst, int n4){
  int idx = blockIdx.x*blockDim.x + threadIdx.x;
  int stride = gridDim.x*blockDim.x;
  for (int i = idx; i < n4; i += stride){
    fvec4 v = *(const fvec4*)(src + (size_t)i*4);
    usvec4 o;
    o[0]=f2bf(v[0]); o[1]=f2bf(v[1]); o[2]=f2bf(v[2]); o[3]=f2bf(v[3]);
    *(usvec4*)(dst + (size_t)i*4) = o;
  }
}

// ---------------- 256x256 GEMM, m201-style 4-phase/K-tile pipeline --------
// C[M,N] = A[M,K] * B[N,K]^T + bias. 512 threads = 8 waves (2M x 4N),
// per-wave 128x64. BK=64; LDS = 2buf x {A,B} x {kk0,kk1} slots of [256][32].
// Phase = {ds_read quadrant; issue 1 stage unit (2 gloads); barrier;
// 16 MFMA (setprio); barrier}. Stage cursor 6 units ahead; vmcnt(4) once
// per K-tile (ph3), vmcnt(0) only at tile nt-2. Slot writes provably
// race-free: target slot's last reader finished >=1 barrier earlier.
template<bool OUT_BF16>
__global__ __launch_bounds__(512, 2)
void gemm256(const unsigned short* __restrict__ A, const unsigned short* __restrict__ Bm,
             const float* __restrict__ bias, void* __restrict__ Cout,
             int M, int N, int K)
{
  __shared__ __align__(16) unsigned short lds[65536];   // 128 KB
  const int tid  = threadIdx.x;
  const int lane = tid & 63;
  const int w    = tid >> 6;          // wave 0..7
  const int wm   = w >> 2;            // 0..1
  const int wn   = w & 3;             // 0..3
  const int l15  = lane & 15, lg = lane >> 4;

  // XCD-aware tile swizzle (grid blocks %8 == 0)
  const int gx  = gridDim.x;
  const int lid = blockIdx.y*gx + blockIdx.x;
  const int nwg = gx*gridDim.y;
  const int qch = nwg >> 3;
  const int sl  = (lid & 7)*qch + (lid >> 3);
  const int bn0 = (sl % gx) * 256;
  const int bm0 = (sl / gx) * 256;

  const int nt = K >> 6;              // K-tiles of 64
  const int NU = nt*4;                // stage units (2 gloads each)

  // stage geometry: unit covers one [256][32] slot = 1024 16B-chunks;
  // instr (w,q) covers chunks (w*2+q)*64 + lane. chunk = row*4 + ((c+(row>>1))&3)
  int rowq[2], cq[2];
  #pragma unroll
  for (int q=0;q<2;q++){
    int u = (w*2+q)*64 + lane;
    rowq[q] = u >> 2;
    cq[q]   = ((u & 3) - (rowq[q] >> 1)) & 3;
  }
  const int rot = (lg + (l15 >> 1)) & 3;   // read-side chunk rotation

  floatx4 acc[8][4];
  #pragma unroll
  for (int m=0;m<8;m++)
    #pragma unroll
    for (int n=0;n<4;n++) acc[m][n] = (floatx4)0.0f;

  // unit u: tau = u>>2; j = u&3: mat = j&1 (0=A,1=B), kkh = j>>1
  auto STAGE_UNIT = [&](int u){
    const int tau = u >> 2, j = u & 3;
    const int mat = j & 1;
    const int kkh = j >> 1;
    const unsigned base = (unsigned)(((((tau & 1)*2 + mat)*2) + kkh) * 8192);
    const unsigned short* src = mat ? Bm : A;
    const int r0 = mat ? bn0 : bm0;
    const size_t kofs = (size_t)tau*64 + kkh*32;
    #pragma unroll
    for (int q=0;q<2;q++)
      gload16(src + (size_t)(r0 + rowq[q])*K + kofs + cq[q]*8, &lds[base + (w*2+q)*512]);
  };

  short8 af[4], bfv[4];
  auto READ_B = [&](int bufb, int kkh){
    const unsigned short* Bs = &lds[((bufb*2+1)*2+kkh)*8192];
    #pragma unroll
    for (int n=0;n<4;n++)
      bfv[n] = *(const short8*)&Bs[(((wn*64 + n*16 + l15)<<2) + rot)*8];
  };
  auto READ_A = [&](int bufb, int kkh, int mh){
    const unsigned short* As = &lds[((bufb*2+0)*2+kkh)*8192];
    #pragma unroll
    for (int m=0;m<4;m++)
      af[m] = *(const short8*)&As[(((wm*128 + (mh*4+m)*16 + l15)<<2) + rot)*8];
  };

  // prologue: 6 units ahead (tile0 complete + tile1 kk0 pair)
  int u = 0;
  for (; u < 6 && u < NU; ++u) STAGE_UNIT(u);
  if (NU > 6) asm volatile("s_waitcnt vmcnt(4)" ::: "memory");
  else        asm volatile("s_waitcnt vmcnt(0)" ::: "memory");
  SBAR(); __builtin_amdgcn_s_barrier(); SBAR();

  for (int t=0; t<nt; ++t){
    const int c = t & 1;
    #pragma unroll
    for (int ph=0; ph<4; ++ph){
      const int kkh = ph >> 1, mh = ph & 1;
      if (mh == 0) READ_B(c, kkh);
      READ_A(c, kkh, mh);
      if (u < NU){ STAGE_UNIT(u); ++u; }
      if (ph == 3){
        if (t < nt-2)       asm volatile("s_waitcnt vmcnt(4)" ::: "memory");
        else if (t == nt-2) asm volatile("s_waitcnt vmcnt(0)" ::: "memory");
      }
      SBAR(); __builtin_amdgcn_s_barrier(); SBAR();
      __builtin_amdgcn_s_setprio(1);
      #pragma unroll
      for (int m=0;m<4;m++)
        #pragma unroll
        for (int n=0;n<4;n++)
          acc[mh*4+m][n] = __builtin_amdgcn_mfma_f32_16x16x32_bf16(af[m], bfv[n], acc[mh*4+m][n], 0, 0, 0);
      __builtin_amdgcn_s_setprio(0);
      SBAR(); __builtin_amdgcn_s_barrier(); SBAR();
    }
  }

  // epilogue
  #pragma unroll
  for (int m=0;m<8;m++){
    #pragma unroll
    for (int n=0;n<4;n++){
      int col = bn0 + wn*64 + n*16 + l15;
      float bs = bias[col];
      #pragma unroll
      for (int r=0;r<4;r++){
        int row = bm0 + wm*128 + m*16 + lg*4 + r;
        float v = acc[m][n][r] + bs;
        if (OUT_BF16) ((unsigned short*)Cout)[(size_t)row*N + col] = f2bf(v);
        else          ((float*)Cout)[(size_t)row*N + col] = v;
      }
    }
  }
}

// ---------------- RoPE + scatter to attention layouts ----------------
// qkv [B,S,7680] bf16 -> Qp,Kp [B,H,S,96] (rope d<32, zero d>=80), Vt [B,H,80,S]
__global__ __launch_bounds__(256)
void rope_scatter(const unsigned short* __restrict__ qkv,
                  const int* __restrict__ pos_ids,
                  unsigned short* __restrict__ Qp, unsigned short* __restrict__ Kp,
                  unsigned short* __restrict__ Vt)
{
  __shared__ float cosb[128*16];
  __shared__ float sinb[128*16];
  __shared__ __align__(16) unsigned short vtile[128*88];
  const int tid = threadIdx.x;
  const int blk = blockIdx.x;
  const int st = blk & 15, h = (blk >> 4) & 31, b = blk >> 9;
  const int s0 = st*128;

  for (int idx = tid; idx < 128*16; idx += 256){
    int sl = idx >> 4, i = idx & 15;
    float p = (float)pos_ids[b*SEQ + s0 + sl];
    float inv = exp2f(-(float)i * (13.287712379549449f/16.0f));
    float ang = p * inv;
    cosb[idx] = cosf(ang);
    sinb[idx] = sinf(ang);
  }
  __syncthreads();

  const size_t qkrow = (size_t)(b*SEQ + s0)*QKV_N;
  const size_t obase = ((size_t)(b*NHEADS + h)*SEQ + s0)*QKS;
  #pragma unroll
  for (int part = 0; part < 2; part++){
    const int cbase = part*HIDDEN + h*HEAD;
    unsigned short* outp = part ? Kp : Qp;
    for (int idx = tid; idx < 128*QKS; idx += 256){
      int sl = idx / QKS, d = idx - sl*QKS;
      const size_t rb = qkrow + (size_t)sl*QKV_N + cbase;
      float v;
      if (d < 16){
        float x1 = bf2f(qkv[rb + d]);
        float x2 = bf2f(qkv[rb + d + 16]);
        v = x1*cosb[sl*16 + d] - x2*sinb[sl*16 + d];
      } else if (d < 32){
        int i = d - 16;
        float x1 = bf2f(qkv[rb + d - 16]);
        float x2 = bf2f(qkv[rb + d]);
        v = x2*cosb[sl*16 + i] + x1*sinb[sl*16 + i];
      } else if (d < HEAD){
        v = bf2f(qkv[rb + d]);
      } else v = 0.0f;
      outp[obase + (size_t)sl*QKS + d] = f2bf(v);
    }
  }

  for (int idx = tid; idx < 128*HEAD; idx += 256){
    int sl = idx / HEAD, d = idx - sl*HEAD;
    vtile[sl*88 + d] = qkv[qkrow + (size_t)sl*QKV_N + 2*HIDDEN + h*HEAD + d];
  }
  __syncthreads();
  const size_t vtb = ((size_t)(b*NHEADS + h)*HEAD)*SEQ + s0;
  for (int idx = tid; idx < HEAD*128; idx += 256){
    int d = idx >> 7, sl = idx & 127;
    Vt[vtb + (size_t)d*SEQ + sl] = vtile[sl*88 + d];
  }
}

// ---------------- flash attention (causal, kv-split, LDS-shared tiles) ----
__global__ __launch_bounds__(256, 4)
void attn_fd(const unsigned short* __restrict__ Qp,
             const unsigned short* __restrict__ Kp,
             const unsigned short* __restrict__ Vt,
             unsigned short* __restrict__ ctx,
             unsigned short* __restrict__ pO,
             float* __restrict__ pML)
{
  __shared__ __align__(16) unsigned short Klds[64*96];    // 12 KB, swizzled
  __shared__ __align__(16) unsigned short Vlds[80*64];    // 10 KB, swizzled
  __shared__ __align__(16) unsigned short p_lds[4][32*36];// 9.2 KB, kk-halves
  const int tid = threadIdx.x;
  const int lane = tid & 63, w = tid >> 6;
  const int l15 = lane & 15, lg = lane >> 4;

  const int bid = blockIdx.x;
  const int xcd = bid & 7, j = bid >> 3;     // j 0..319
  const int bh  = (j/40)*8 + xcd;
  const int tr  = j - (j/40)*40;

  int qt, part, np;
  if (tr < 16)      { qt = 12 + (tr>>2); part = tr & 3; np = 4; }
  else if (tr < 28) { int t = tr-16; int q3 = t/3; qt = 8 + q3; part = t - q3*3; np = 3; }
  else if (tr < 36) { int t = tr-28; qt = 4 + (t>>1); part = t & 1; np = 2; }
  else              { qt = tr - 36; part = 0; np = 1; }
  const int nk  = 2*qt + 2;
  const int kt0 = (part*nk)/np, kt1 = ((part+1)*nk)/np;
  const int q0  = qt*128 + w*32;

  const unsigned short* Qb = Qp + ((size_t)bh*SEQ)*QKS;
  const unsigned short* Kb = Kp + ((size_t)bh*SEQ)*QKS;
  const unsigned short* Vb = Vt + ((size_t)bh*HEAD)*SEQ;

  short8 qf[2][3];
  #pragma unroll
  for (int mi=0; mi<2; mi++)
    #pragma unroll
    for (int kc=0; kc<3; kc++)
      qf[mi][kc] = *(const short8*)&Qb[(size_t)(q0 + mi*16 + l15)*QKS + kc*32 + lg*8];

  int ksrow[3], ksc[3];
  #pragma unroll
  for (int t=0;t<3;t++){
    int ci = (w*3 + t)*64 + lane;       // K chunk 0..767
    int row = ci/12, c = ci - row*12;
    ksrow[t] = row;
    ksc[t]   = (c ^ (row & 3))*8;
  }
  int vsrow[3], vsc[3];
  #pragma unroll
  for (int t=0;t<3;t++){
    int i = w + 4*t;                    // V instr 0..9
    int row = i*8 + (lane >> 3), c = lane & 7;
    vsrow[t] = row;
    vsc[t]   = (c ^ (row & 7))*8;
  }

  float mrun[2] = {-3e38f, -3e38f};
  float lrun[2] = {0.0f, 0.0f};
  floatx4 oacc[2][5];
  #pragma unroll
  for (int mi=0;mi<2;mi++)
    #pragma unroll
    for (int di=0;di<5;di++) oacc[mi][di] = (floatx4)0.0f;

  const float SC = 0.1118033988749895f * 1.4426950408889634f; // 1/sqrt(80)*log2(e)

  for (int kt = kt0; kt < kt1; kt++){
    #pragma unroll
    for (int t=0;t<3;t++)
      gload16(Kb + (size_t)(kt*64 + ksrow[t])*QKS + ksc[t], &Klds[(w*3+t)*512]);
    #pragma unroll
    for (int t=0;t<3;t++){
      int i = w + 4*t;
      if (i < 10)
        gload16(Vb + (size_t)vsrow[t]*SEQ + kt*64 + vsc[t], &Vlds[i*512]);
    }
    __syncthreads();

    if (kt*64 <= q0 + 31){
      floatx4 sacc[2][4];
      #pragma unroll
      for (int mi=0;mi<2;mi++)
        #pragma unroll
        for (int ni=0;ni<4;ni++) sacc[mi][ni] = (floatx4)0.0f;

      __builtin_amdgcn_s_setprio(1);
      #pragma unroll
      for (int kc=0; kc<3; kc++){
        short8 kf[4];
        #pragma unroll
        for (int ni=0; ni<4; ni++){
          int r = ni*16 + l15;
          kf[ni] = *(const short8*)&Klds[r*96 + (((kc*4+lg) ^ (r & 3))<<3)];
        }
        #pragma unroll
        for (int mi=0; mi<2; mi++)
          #pragma unroll
          for (int ni=0; ni<4; ni++)
            sacc[mi][ni] = __builtin_amdgcn_mfma_f32_16x16x32_bf16(kf[ni], qf[mi][kc], sacc[mi][ni], 0, 0, 0);
      }
      __builtin_amdgcn_s_setprio(0);

      if (kt*64 + 63 > q0){
        #pragma unroll
        for (int mi=0; mi<2; mi++){
          int qrow = q0 + mi*16 + l15;
          #pragma unroll
          for (int ni=0; ni<4; ni++){
            int kb = kt*64 + ni*16 + lg*4;
            #pragma unroll
            for (int r=0; r<4; r++)
              if (kb + r > qrow) sacc[mi][ni][r] = -3e38f;
          }
        }
      }

      #pragma unroll
      for (int mi=0; mi<2; mi++){
        float pm = -3e38f;
        #pragma unroll
        for (int ni=0; ni<4; ni++)
          #pragma unroll
          for (int r=0; r<4; r++) pm = fmaxf(pm, sacc[mi][ni][r]);
        pm = fmaxf(pm, __shfl_xor(pm, 16));
        pm = fmaxf(pm, __shfl_xor(pm, 32));
        float mold = mrun[mi];
        float mnew = fmaxf(mold, pm);
        float msc  = mnew*SC;
        float alpha = __builtin_amdgcn_exp2f(mold*SC - msc);
        float rs = 0.0f;
        #pragma unroll
        for (int ni=0; ni<4; ni++)
          #pragma unroll
          for (int r=0; r<4; r++){
            float p = __builtin_amdgcn_exp2f(sacc[mi][ni][r]*SC - msc);
            sacc[mi][ni][r] = p;
            rs += p;
          }
        rs += __shfl_xor(rs, 16);
        rs += __shfl_xor(rs, 32);
        lrun[mi] = lrun[mi]*alpha + rs;
        mrun[mi] = mnew;
        #pragma unroll
        for (int di=0; di<5; di++) oacc[mi][di] *= alpha;
      }

      #pragma unroll
      for (int kk=0; kk<2; kk++){
        #pragma unroll
        for (int mi=0; mi<2; mi++)
          #pragma unroll
          for (int nl=0; nl<2; nl++){
            int ni = kk*2 + nl;
            uint2v pk;
            pk[0] = cvt_pk_bf16(sacc[mi][ni][0], sacc[mi][ni][1]);
            pk[1] = cvt_pk_bf16(sacc[mi][ni][2], sacc[mi][ni][3]);
            *(uint2v*)&p_lds[w][(mi*16 + l15)*36 + nl*16 + lg*4] = pk;
          }
        __builtin_amdgcn_s_setprio(1);
        short8 pa[2];
        #pragma unroll
        for (int mi=0;mi<2;mi++)
          pa[mi] = *(const short8*)&p_lds[w][(mi*16 + l15)*36 + lg*8];
        #pragma unroll
        for (int di=0; di<5; di++){
          int r = di*16 + l15;
          short8 vf = *(const short8*)&Vlds[r*64 + (((kk*4+lg) ^ (r & 7))<<3)];
          #pragma unroll
          for (int mi=0;mi<2;mi++)
            oacc[mi][di] = __builtin_amdgcn_mfma_f32_16x16x32_bf16(vf, pa[mi], oacc[mi][di], 0, 0, 0);
        }
        __builtin_amdgcn_s_setprio(0);
      }
    }
    __syncthreads();
  }

  const int b = bh >> 5, h = bh & 31;
  if (np == 1){
    #pragma unroll
    for (int mi=0;mi<2;mi++){
      float inv = 1.0f/lrun[mi];
      size_t crow = ((size_t)(b*SEQ + q0 + mi*16 + l15))*HIDDEN + h*HEAD;
      #pragma unroll
      for (int di=0;di<5;di++){
        uint2v pk;
        pk[0] = cvt_pk_bf16(oacc[mi][di][0]*inv, oacc[mi][di][1]*inv);
        pk[1] = cvt_pk_bf16(oacc[mi][di][2]*inv, oacc[mi][di][3]*inv);
        *(uint2v*)&ctx[crow + di*16 + lg*4] = pk;
      }
    }
  } else {
    int base;
    if (np == 2)      base = (qt-4)*2;
    else if (np == 3) base = 8 + (qt-8)*3;
    else              base = 20 + (qt-12)*4;
    const int pslot = bh*PART_SLOTS + base + part;
    unsigned short* Ob = pO + (size_t)pslot*128*HEAD;
    #pragma unroll
    for (int mi=0;mi<2;mi++){
      int grow = w*32 + mi*16 + l15;
      #pragma unroll
      for (int di=0;di<5;di++){
        uint2v pk;
        pk[0] = cvt_pk_bf16(oacc[mi][di][0], oacc[mi][di][1]);
        pk[1] = cvt_pk_bf16(oacc[mi][di][2], oacc[mi][di][3]);
        *(uint2v*)&Ob[grow*HEAD + di*16 + lg*4] = pk;
      }
      if (lg == 0){
        float* mlb = pML + ((size_t)pslot*128 + grow)*2;
        mlb[0] = mrun[mi];
        mlb[1] = lrun[mi];
      }
    }
  }
}

// ---------------- combine partials (coalesced flat-tile reads) ----------------
__global__ __launch_bounds__(256)
void attn_combine(const unsigned short* __restrict__ pO, const float* __restrict__ pML,
                  unsigned short* __restrict__ ctx)
{
  const int bid = blockIdx.x;              // 64*12
  const int bh = bid / 12, qt = 4 + (bid - (bid/12)*12);
  int base, np;
  if (qt < 8)       { base = (qt-4)*2;       np = 2; }
  else if (qt < 12) { base = 8 + (qt-8)*3;   np = 3; }
  else              { base = 20 + (qt-12)*4; np = 4; }
  const int slot0 = bh*PART_SLOTS + base;
  const float SC = 0.1118033988749895f * 1.4426950408889634f;
  const int b = bh >> 5, h = bh & 31;

  #pragma unroll
  for (int c = 0; c < 5; c++){
    const int e   = c*2048 + threadIdx.x*8;   // element in flat 128x80 tile
    const int row = e / 80, d = e - row*80;   // 80%8==0: never crosses rows

    float m[4], l[4], ms = -3e38f;
    for (int p=0;p<np;p++){
      const float* mlb = pML + ((size_t)(slot0+p)*128 + row)*2;
      m[p] = mlb[0]; l[p] = mlb[1];
      ms = fmaxf(ms, m[p]);
    }
    float wgt[4], lsum = 0.0f;
    for (int p=0;p<np;p++){
      wgt[p] = exp2f((m[p]-ms)*SC);
      lsum += wgt[p]*l[p];
    }
    const float inv = 1.0f/lsum;

    float acc[8] = {0,0,0,0,0,0,0,0};
    for (int p=0;p<np;p++){
      short8 v = *(const short8*)&pO[(size_t)(slot0+p)*128*HEAD + e];
      #pragma unroll
      for (int j=0;j<8;j++) acc[j] += wgt[p]*bf2f((unsigned short)v[j]);
    }
    short8 o;
    #pragma unroll
    for (int j=0;j<8;j++) o[j] = (short)f2bf(acc[j]*inv);
    *(short8*)&ctx[((size_t)(b*SEQ + qt*128 + row))*HIDDEN + h*HEAD + d] = o;
  }
}

// ---------------- launch ----------------
extern "C" void kernel_launch(void* const* d_in, const int* in_sizes, int n_in,
                              void* d_out, int out_size, void* d_ws, size_t ws_size,
                              hipStream_t stream)
{
  const int*   pos  = (const int*)  d_in[0];
  const float* hid  = (const float*)d_in[1];
  const float* wqkv = (const float*)d_in[2];
  const float* bqkv = (const float*)d_in[3];
  const float* outw = (const float*)d_in[4];
  const float* outb = (const float*)d_in[5];

  char* ws = (char*)d_ws;
  size_t off = 0;
  auto alloc = [&](size_t bytes)->void*{
    void* p = ws + off; off += (bytes + 255) & ~(size_t)255; return p;
  };
  unsigned short* hid_bf  = (unsigned short*)alloc((size_t)M_TOTAL*HIDDEN*2);   // reused as ctx
  unsigned short* wqkv_bf = (unsigned short*)alloc((size_t)QKV_N*HIDDEN*2);
  unsigned short* outw_bf = (unsigned short*)alloc((size_t)HIDDEN*HIDDEN*2);
  unsigned short* qkv_bf  = (unsigned short*)alloc((size_t)M_TOTAL*QKV_N*2);    // reused as partials
  unsigned short* Qp      = (unsigned short*)alloc((size_t)BATCH*NHEADS*SEQ*QKS*2);
  unsigned short* Kp      = (unsigned short*)alloc((size_t)BATCH*NHEADS*SEQ*QKS*2);
  unsigned short* Vt      = (unsigned short*)alloc((size_t)BATCH*NHEADS*HEAD*SEQ*2);
  if (off > ws_size) return;

  unsigned short* pO  = qkv_bf;                                            // 47.2 MB
  float*          pML = (float*)(qkv_bf + (size_t)64*PART_SLOTS*128*HEAD); // 2.36 MB

  convert_f32_bf16<<<dim3(1024), dim3(256), 0, stream>>>(hid,  hid_bf,  M_TOTAL*HIDDEN/4);
  convert_f32_bf16<<<dim3(2048), dim3(256), 0, stream>>>(wqkv, wqkv_bf, QKV_N*HIDDEN/4);
  convert_f32_bf16<<<dim3(1024), dim3(256), 0, stream>>>(outw, outw_bf, HIDDEN*HIDDEN/4);

  gemm256<true><<<dim3(QKV_N/256, M_TOTAL/256), dim3(512), 0, stream>>>(
      hid_bf, wqkv_bf, bqkv, (void*)qkv_bf, M_TOTAL, QKV_N, HIDDEN);

  rope_scatter<<<dim3(BATCH*NHEADS*16), dim3(256), 0, stream>>>(qkv_bf, pos, Qp, Kp, Vt);

  unsigned short* ctx = hid_bf;  // hidden_bf dead after QKV GEMM
  attn_fd<<<dim3(2560), dim3(256), 0, stream>>>(Qp, Kp, Vt, ctx, pO, pML);
  attn_combine<<<dim3(64*12), dim3(256), 0, stream>>>(pO, pML, ctx);

  gemm256<false><<<dim3(HIDDEN/256, M_TOTAL/256), dim3(512), 0, stream>>>(
      ctx, outw_bf, outb, d_out, M_TOTAL, HIDDEN, HIDDEN);
}

// Round 14
// 482.817 us; speedup vs baseline: 1.1751x; 1.1738x over previous
//
#include <hip/hip_runtime.h>
#include <stdint.h>

#define HIDDEN  2560
#define NHEADS  32
#define HEAD    80
#define QKS     96           // Q/K padded head stride (3 x 32 for MFMA K)
#define SEQ     2048
#define BATCH   2
#define M_TOTAL (BATCH*SEQ)  // 4096
#define QKV_N   (3*HIDDEN)   // 7680
#define PART_SLOTS 36

typedef __attribute__((ext_vector_type(8))) short  short8;
typedef __attribute__((ext_vector_type(4))) float  floatx4;
typedef __attribute__((ext_vector_type(4))) float  fvec4;
typedef __attribute__((ext_vector_type(4))) unsigned short usvec4;
typedef __attribute__((ext_vector_type(2))) unsigned int uint2v;

#define SBAR() __builtin_amdgcn_sched_barrier(0)

__device__ __forceinline__ unsigned short f2bf(float x){
  union { float f; unsigned u; } v; v.f = x;
  unsigned r = v.u + 0x7fffu + ((v.u >> 16) & 1u);
  return (unsigned short)(r >> 16);
}
__device__ __forceinline__ float bf2f(unsigned short h){
  union { unsigned u; float f; } v; v.u = ((unsigned)h) << 16;
  return v.f;
}
__device__ __forceinline__ unsigned cvt_pk_bf16(float lo, float hi){
  unsigned r;
  asm volatile("v_cvt_pk_bf16_f32 %0, %1, %2" : "=v"(r) : "v"(lo), "v"(hi));
  return r;
}
__device__ __forceinline__ void gload16(const void* g, void* l){
  __builtin_amdgcn_global_load_lds(
    (const __attribute__((address_space(1))) void*)g,
    (__attribute__((address_space(3))) void*)l, 16, 0, 0);
}

// ---------------- f32 -> bf16 convert ----------------
__global__ __launch_bounds__(256)
void convert_f32_bf16(const float* __restrict__ src, unsigned short* __restrict__ dst, int n4){
  int idx = blockIdx.x*blockDim.x + threadIdx.x;
  int stride = gridDim.x*blockDim.x;
  for (int i = idx; i < n4; i += stride){
    fvec4 v = *(const fvec4*)(src + (size_t)i*4);
    usvec4 o;
    o[0]=f2bf(v[0]); o[1]=f2bf(v[1]); o[2]=f2bf(v[2]); o[3]=f2bf(v[3]);
    *(usvec4*)(dst + (size_t)i*4) = o;
  }
}

// ---------------- 256x256 GEMM, counted-vmcnt, compiler-interleaved --------
// (r11 configuration: best measured — 182 us QKV, MfmaUtil 39).
template<bool OUT_BF16>
__global__ __launch_bounds__(512, 2)
void gemm256(const unsigned short* __restrict__ A, const unsigned short* __restrict__ Bm,
             const float* __restrict__ bias, void* __restrict__ Cout,
             int M, int N, int K)
{
  __shared__ __align__(16) unsigned short lds[65536];   // 128 KB
  const int tid  = threadIdx.x;
  const int lane = tid & 63;
  const int w    = tid >> 6;          // wave 0..7
  const int wm   = w >> 2;            // 0..1
  const int wn   = w & 3;             // 0..3
  const int l15  = lane & 15, lg = lane >> 4;

  const int gx  = gridDim.x;
  const int lid = blockIdx.y*gx + blockIdx.x;
  const int nwg = gx*gridDim.y;
  const int qch = nwg >> 3;
  const int sl  = (lid & 7)*qch + (lid >> 3);
  const int bn0 = (sl % gx) * 256;
  const int bm0 = (sl / gx) * 256;

  const int nt = K >> 6;              // K-tiles of 64

  int rowq[2], cq[2];
  #pragma unroll
  for (int q=0;q<2;q++){
    int u = (w*2+q)*64 + lane;
    rowq[q] = u >> 2;
    cq[q]   = ((u & 3) - (rowq[q] >> 1)) & 3;
  }
  const int rot = (lg + (l15 >> 1)) & 3;   // read-side chunk rotation

  floatx4 acc[8][4];
  #pragma unroll
  for (int m=0;m<8;m++)
    #pragma unroll
    for (int n=0;n<4;n++) acc[m][n] = (floatx4)0.0f;

  auto STAGE = [&](int tau, int kkh){
    const int bufb = tau & 1;
    const size_t kofs = (size_t)tau*64 + kkh*32;
    const unsigned sA = (unsigned)(((bufb*2 + 0)*2 + kkh) * 8192);
    const unsigned sB = (unsigned)(((bufb*2 + 1)*2 + kkh) * 8192);
    #pragma unroll
    for (int q=0;q<2;q++){
      gload16(A  + (size_t)(bm0 + rowq[q])*K + kofs + cq[q]*8, &lds[sA + (w*2+q)*512]);
      gload16(Bm + (size_t)(bn0 + rowq[q])*K + kofs + cq[q]*8, &lds[sB + (w*2+q)*512]);
    }
  };
  auto COMPUTE = [&](int bufb, int kkh){
    const unsigned short* As = &lds[((bufb*2+0)*2+kkh)*8192];
    const unsigned short* Bs = &lds[((bufb*2+1)*2+kkh)*8192];
    short8 af[8], bfv[4];
    __builtin_amdgcn_s_setprio(1);
    #pragma unroll
    for (int n=0;n<4;n++)
      bfv[n] = *(const short8*)&Bs[(((wn*64 + n*16 + l15)<<2) + rot)*8];
    #pragma unroll
    for (int m=0;m<8;m++)
      af[m] = *(const short8*)&As[(((wm*128 + m*16 + l15)<<2) + rot)*8];
    #pragma unroll
    for (int m=0;m<8;m++)
      #pragma unroll
      for (int n=0;n<4;n++)
        acc[m][n] = __builtin_amdgcn_mfma_f32_16x16x32_bf16(af[m], bfv[n], acc[m][n], 0, 0, 0);
    __builtin_amdgcn_s_setprio(0);
  };

  // prologue: issue (0,kk0),(0,kk1),(1,kk0); oldest group landed at vmcnt(8)
  STAGE(0,0);
  STAGE(0,1);
  STAGE(1,0);
  asm volatile("s_waitcnt vmcnt(8)" ::: "memory");
  __builtin_amdgcn_s_barrier(); SBAR();

  for (int t=0; t<nt; ++t){
    const int c = t & 1;
    // ---- phase A: stage (t+1,kk1), compute kk0 ----
    if (t+1 < nt) STAGE(t+1, 1);
    COMPUTE(c, 0);
    if (t+1 < nt) asm volatile("s_waitcnt vmcnt(8)" ::: "memory");
    else          asm volatile("s_waitcnt vmcnt(0)" ::: "memory");
    __builtin_amdgcn_s_barrier(); SBAR();
    // ---- phase B: stage (t+2,kk0), compute kk1 ----
    if (t+2 < nt) STAGE(t+2, 0);
    COMPUTE(c, 1);
    if (t+1 < nt){
      if (t+2 < nt) asm volatile("s_waitcnt vmcnt(8)" ::: "memory");
      else          asm volatile("s_waitcnt vmcnt(4)" ::: "memory");
      __builtin_amdgcn_s_barrier(); SBAR();
    }
  }

  // epilogue
  #pragma unroll
  for (int m=0;m<8;m++){
    #pragma unroll
    for (int n=0;n<4;n++){
      int col = bn0 + wn*64 + n*16 + l15;
      float bs = bias[col];
      #pragma unroll
      for (int r=0;r<4;r++){
        int row = bm0 + wm*128 + m*16 + lg*4 + r;
        float v = acc[m][n][r] + bs;
        if (OUT_BF16) ((unsigned short*)Cout)[(size_t)row*N + col] = f2bf(v);
        else          ((float*)Cout)[(size_t)row*N + col] = v;
      }
    }
  }
}

// ---------------- RoPE + scatter to attention layouts ----------------
// qkv [B,S,7680] bf16 -> Qp,Kp [B,H,S,96] (rope d<32, zero d>=80), Vt [B,H,80,S]
__global__ __launch_bounds__(256)
void rope_scatter(const unsigned short* __restrict__ qkv,
                  const int* __restrict__ pos_ids,
                  unsigned short* __restrict__ Qp, unsigned short* __restrict__ Kp,
                  unsigned short* __restrict__ Vt)
{
  __shared__ float cosb[128*16];
  __shared__ float sinb[128*16];
  __shared__ __align__(16) unsigned short vtile[128*88];
  const int tid = threadIdx.x;
  const int blk = blockIdx.x;
  const int st = blk & 15, h = (blk >> 4) & 31, b = blk >> 9;
  const int s0 = st*128;

  for (int idx = tid; idx < 128*16; idx += 256){
    int sl = idx >> 4, i = idx & 15;
    float p = (float)pos_ids[b*SEQ + s0 + sl];
    float inv = exp2f(-(float)i * (13.287712379549449f/16.0f));
    float ang = p * inv;
    cosb[idx] = cosf(ang);
    sinb[idx] = sinf(ang);
  }
  __syncthreads();

  const size_t qkrow = (size_t)(b*SEQ + s0)*QKV_N;
  const size_t obase = ((size_t)(b*NHEADS + h)*SEQ + s0)*QKS;
  #pragma unroll
  for (int part = 0; part < 2; part++){
    const int cbase = part*HIDDEN + h*HEAD;
    unsigned short* outp = part ? Kp : Qp;
    for (int idx = tid; idx < 128*QKS; idx += 256){
      int sl = idx / QKS, d = idx - sl*QKS;
      const size_t rb = qkrow + (size_t)sl*QKV_N + cbase;
      float v;
      if (d < 16){
        float x1 = bf2f(qkv[rb + d]);
        float x2 = bf2f(qkv[rb + d + 16]);
        v = x1*cosb[sl*16 + d] - x2*sinb[sl*16 + d];
      } else if (d < 32){
        int i = d - 16;
        float x1 = bf2f(qkv[rb + d - 16]);
        float x2 = bf2f(qkv[rb + d]);
        v = x2*cosb[sl*16 + i] + x1*sinb[sl*16 + i];
      } else if (d < HEAD){
        v = bf2f(qkv[rb + d]);
      } else v = 0.0f;
      outp[obase + (size_t)sl*QKS + d] = f2bf(v);
    }
  }

  for (int idx = tid; idx < 128*HEAD; idx += 256){
    int sl = idx / HEAD, d = idx - sl*HEAD;
    vtile[sl*88 + d] = qkv[qkrow + (size_t)sl*QKV_N + 2*HIDDEN + h*HEAD + d];
  }
  __syncthreads();
  const size_t vtb = ((size_t)(b*NHEADS + h)*HEAD)*SEQ + s0;
  for (int idx = tid; idx < HEAD*128; idx += 256){
    int d = idx >> 7, sl = idx & 127;
    Vt[vtb + (size_t)d*SEQ + sl] = vtile[sl*88 + d];
  }
}

// ---------------- flash attention (causal, kv-split, double-buffered LDS) --
// block-task = (bh, 128-row q-tile, kv-part of <=8 key-tiles). 40 tasks/bh.
// T3-minimum 2-phase: STAGE(kt+1, buf^1) issued BEFORE compute(buf); single
// end-of-tile __syncthreads drains — stage latency hides under compute.
__global__ __launch_bounds__(256, 4)
void attn_fd(const unsigned short* __restrict__ Qp,
             const unsigned short* __restrict__ Kp,
             const unsigned short* __restrict__ Vt,
             unsigned short* __restrict__ ctx,
             unsigned short* __restrict__ pO,
             float* __restrict__ pML)
{
  __shared__ __align__(16) unsigned short Klds[2][64*96];  // 24 KB, swizzled
  __shared__ __align__(16) unsigned short Vlds[2][80*64];  // 20 KB, swizzled
  __shared__ __align__(16) unsigned short p_lds[4][32*36]; // 9.2 KB
  const int tid = threadIdx.x;
  const int lane = tid & 63, w = tid >> 6;
  const int l15 = lane & 15, lg = lane >> 4;

  const int bid = blockIdx.x;
  const int xcd = bid & 7, j = bid >> 3;     // j 0..319
  const int bh  = (j/40)*8 + xcd;
  const int tr  = j - (j/40)*40;

  int qt, part, np;
  if (tr < 16)      { qt = 12 + (tr>>2); part = tr & 3; np = 4; }
  else if (tr < 28) { int t = tr-16; int q3 = t/3; qt = 8 + q3; part = t - q3*3; np = 3; }
  else if (tr < 36) { int t = tr-28; qt = 4 + (t>>1); part = t & 1; np = 2; }
  else              { qt = tr - 36; part = 0; np = 1; }
  const int nk  = 2*qt + 2;
  const int kt0 = (part*nk)/np, kt1 = ((part+1)*nk)/np;
  const int q0  = qt*128 + w*32;

  const unsigned short* Qb = Qp + ((size_t)bh*SEQ)*QKS;
  const unsigned short* Kb = Kp + ((size_t)bh*SEQ)*QKS;
  const unsigned short* Vb = Vt + ((size_t)bh*HEAD)*SEQ;

  short8 qf[2][3];
  #pragma unroll
  for (int mi=0; mi<2; mi++)
    #pragma unroll
    for (int kc=0; kc<3; kc++)
      qf[mi][kc] = *(const short8*)&Qb[(size_t)(q0 + mi*16 + l15)*QKS + kc*32 + lg*8];

  int ksrow[3], ksc[3];
  #pragma unroll
  for (int t=0;t<3;t++){
    int ci = (w*3 + t)*64 + lane;       // K chunk 0..767
    int row = ci/12, c = ci - row*12;
    ksrow[t] = row;
    ksc[t]   = (c ^ (row & 3))*8;
  }
  int vsrow[3], vsc[3];
  #pragma unroll
  for (int t=0;t<3;t++){
    int i = w + 4*t;                    // V instr 0..9
    int row = i*8 + (lane >> 3), c = lane & 7;
    vsrow[t] = row;
    vsc[t]   = (c ^ (row & 7))*8;
  }

  auto STAGE_T = [&](int kt, int bb){
    #pragma unroll
    for (int t=0;t<3;t++)
      gload16(Kb + (size_t)(kt*64 + ksrow[t])*QKS + ksc[t], &Klds[bb][(w*3+t)*512]);
    #pragma unroll
    for (int t=0;t<3;t++){
      int i = w + 4*t;
      if (i < 10)
        gload16(Vb + (size_t)vsrow[t]*SEQ + kt*64 + vsc[t], &Vlds[bb][i*512]);
    }
  };

  float mrun[2] = {-3e38f, -3e38f};
  float lrun[2] = {0.0f, 0.0f};
  floatx4 oacc[2][5];
  #pragma unroll
  for (int mi=0;mi<2;mi++)
    #pragma unroll
    for (int di=0;di<5;di++) oacc[mi][di] = (floatx4)0.0f;

  const float SC = 0.1118033988749895f * 1.4426950408889634f; // 1/sqrt(80)*log2(e)

  // prologue: stage first tile, publish
  STAGE_T(kt0, 0);
  __syncthreads();   // compiler drains vmcnt(0) lgkmcnt(0) before barrier

  for (int kt = kt0; kt < kt1; kt++){
    const int cur = (kt - kt0) & 1;
    // issue next tile into the other buffer (its last readers finished
    // before the barrier that ended iteration kt-1 -> race-free)
    if (kt+1 < kt1) STAGE_T(kt+1, cur^1);

    if (kt*64 <= q0 + 31){
      floatx4 sacc[2][4];
      #pragma unroll
      for (int mi=0;mi<2;mi++)
        #pragma unroll
        for (int ni=0;ni<4;ni++) sacc[mi][ni] = (floatx4)0.0f;

      __builtin_amdgcn_s_setprio(1);
      #pragma unroll
      for (int kc=0; kc<3; kc++){
        short8 kf[4];
        #pragma unroll
        for (int ni=0; ni<4; ni++){
          int r = ni*16 + l15;
          kf[ni] = *(const short8*)&Klds[cur][r*96 + (((kc*4+lg) ^ (r & 3))<<3)];
        }
        #pragma unroll
        for (int mi=0; mi<2; mi++)
          #pragma unroll
          for (int ni=0; ni<4; ni++)
            sacc[mi][ni] = __builtin_amdgcn_mfma_f32_16x16x32_bf16(kf[ni], qf[mi][kc], sacc[mi][ni], 0, 0, 0);
      }
      __builtin_amdgcn_s_setprio(0);

      if (kt*64 + 63 > q0){
        #pragma unroll
        for (int mi=0; mi<2; mi++){
          int qrow = q0 + mi*16 + l15;
          #pragma unroll
          for (int ni=0; ni<4; ni++){
            int kb = kt*64 + ni*16 + lg*4;
            #pragma unroll
            for (int r=0; r<4; r++)
              if (kb + r > qrow) sacc[mi][ni][r] = -3e38f;
          }
        }
      }

      #pragma unroll
      for (int mi=0; mi<2; mi++){
        float pm = -3e38f;
        #pragma unroll
        for (int ni=0; ni<4; ni++)
          #pragma unroll
          for (int r=0; r<4; r++) pm = fmaxf(pm, sacc[mi][ni][r]);
        pm = fmaxf(pm, __shfl_xor(pm, 16));
        pm = fmaxf(pm, __shfl_xor(pm, 32));
        float mold = mrun[mi];
        float mnew = fmaxf(mold, pm);
        float msc  = mnew*SC;
        float alpha = __builtin_amdgcn_exp2f(mold*SC - msc);
        float rs = 0.0f;
        #pragma unroll
        for (int ni=0; ni<4; ni++)
          #pragma unroll
          for (int r=0; r<4; r++){
            float p = __builtin_amdgcn_exp2f(sacc[mi][ni][r]*SC - msc);
            sacc[mi][ni][r] = p;
            rs += p;
          }
        rs += __shfl_xor(rs, 16);
        rs += __shfl_xor(rs, 32);
        lrun[mi] = lrun[mi]*alpha + rs;
        mrun[mi] = mnew;
        #pragma unroll
        for (int di=0; di<5; di++) oacc[mi][di] *= alpha;
      }

      #pragma unroll
      for (int kk=0; kk<2; kk++){
        #pragma unroll
        for (int mi=0; mi<2; mi++)
          #pragma unroll
          for (int nl=0; nl<2; nl++){
            int ni = kk*2 + nl;
            uint2v pk;
            pk[0] = cvt_pk_bf16(sacc[mi][ni][0], sacc[mi][ni][1]);
            pk[1] = cvt_pk_bf16(sacc[mi][ni][2], sacc[mi][ni][3]);
            *(uint2v*)&p_lds[w][(mi*16 + l15)*36 + nl*16 + lg*4] = pk;
          }
        __builtin_amdgcn_s_setprio(1);
        short8 pa[2];
        #pragma unroll
        for (int mi=0;mi<2;mi++)
          pa[mi] = *(const short8*)&p_lds[w][(mi*16 + l15)*36 + lg*8];
        #pragma unroll
        for (int di=0; di<5; di++){
          int r = di*16 + l15;
          short8 vf = *(const short8*)&Vlds[cur][r*64 + (((kk*4+lg) ^ (r & 7))<<3)];
          #pragma unroll
          for (int mi=0;mi<2;mi++)
            oacc[mi][di] = __builtin_amdgcn_mfma_f32_16x16x32_bf16(vf, pa[mi], oacc[mi][di], 0, 0, 0);
        }
        __builtin_amdgcn_s_setprio(0);
      }
    }
    __syncthreads();   // drains this tile's reads + next tile's stage writes
  }

  const int b = bh >> 5, h = bh & 31;
  if (np == 1){
    #pragma unroll
    for (int mi=0;mi<2;mi++){
      float inv = 1.0f/lrun[mi];
      size_t crow = ((size_t)(b*SEQ + q0 + mi*16 + l15))*HIDDEN + h*HEAD;
      #pragma unroll
      for (int di=0;di<5;di++){
        uint2v pk;
        pk[0] = cvt_pk_bf16(oacc[mi][di][0]*inv, oacc[mi][di][1]*inv);
        pk[1] = cvt_pk_bf16(oacc[mi][di][2]*inv, oacc[mi][di][3]*inv);
        *(uint2v*)&ctx[crow + di*16 + lg*4] = pk;
      }
    }
  } else {
    int base;
    if (np == 2)      base = (qt-4)*2;
    else if (np == 3) base = 8 + (qt-8)*3;
    else              base = 20 + (qt-12)*4;
    const int pslot = bh*PART_SLOTS + base + part;
    unsigned short* Ob = pO + (size_t)pslot*128*HEAD;
    #pragma unroll
    for (int mi=0;mi<2;mi++){
      int grow = w*32 + mi*16 + l15;
      #pragma unroll
      for (int di=0;di<5;di++){
        uint2v pk;
        pk[0] = cvt_pk_bf16(oacc[mi][di][0], oacc[mi][di][1]);
        pk[1] = cvt_pk_bf16(oacc[mi][di][2], oacc[mi][di][3]);
        *(uint2v*)&Ob[grow*HEAD + di*16 + lg*4] = pk;
      }
      if (lg == 0){
        float* mlb = pML + ((size_t)pslot*128 + grow)*2;
        mlb[0] = mrun[mi];
        mlb[1] = lrun[mi];
      }
    }
  }
}

// ---------------- combine partials (coalesced flat-tile reads) ----------------
__global__ __launch_bounds__(256)
void attn_combine(const unsigned short* __restrict__ pO, const float* __restrict__ pML,
                  unsigned short* __restrict__ ctx)
{
  const int bid = blockIdx.x;              // 64*12
  const int bh = bid / 12, qt = 4 + (bid - (bid/12)*12);
  int base, np;
  if (qt < 8)       { base = (qt-4)*2;       np = 2; }
  else if (qt < 12) { base = 8 + (qt-8)*3;   np = 3; }
  else              { base = 20 + (qt-12)*4; np = 4; }
  const int slot0 = bh*PART_SLOTS + base;
  const float SC = 0.1118033988749895f * 1.4426950408889634f;
  const int b = bh >> 5, h = bh & 31;

  #pragma unroll
  for (int c = 0; c < 5; c++){
    const int e   = c*2048 + threadIdx.x*8;   // element in flat 128x80 tile
    const int row = e / 80, d = e - row*80;   // 80%8==0: never crosses rows

    float m[4], l[4], ms = -3e38f;
    for (int p=0;p<np;p++){
      const float* mlb = pML + ((size_t)(slot0+p)*128 + row)*2;
      m[p] = mlb[0]; l[p] = mlb[1];
      ms = fmaxf(ms, m[p]);
    }
    float wgt[4], lsum = 0.0f;
    for (int p=0;p<np;p++){
      wgt[p] = exp2f((m[p]-ms)*SC);
      lsum += wgt[p]*l[p];
    }
    const float inv = 1.0f/lsum;

    float acc[8] = {0,0,0,0,0,0,0,0};
    for (int p=0;p<np;p++){
      short8 v = *(const short8*)&pO[(size_t)(slot0+p)*128*HEAD + e];
      #pragma unroll
      for (int j=0;j<8;j++) acc[j] += wgt[p]*bf2f((unsigned short)v[j]);
    }
    short8 o;
    #pragma unroll
    for (int j=0;j<8;j++) o[j] = (short)f2bf(acc[j]*inv);
    *(short8*)&ctx[((size_t)(b*SEQ + qt*128 + row))*HIDDEN + h*HEAD + d] = o;
  }
}

// ---------------- launch ----------------
extern "C" void kernel_launch(void* const* d_in, const int* in_sizes, int n_in,
                              void* d_out, int out_size, void* d_ws, size_t ws_size,
                              hipStream_t stream)
{
  const int*   pos  = (const int*)  d_in[0];
  const float* hid  = (const float*)d_in[1];
  const float* wqkv = (const float*)d_in[2];
  const float* bqkv = (const float*)d_in[3];
  const float* outw = (const float*)d_in[4];
  const float* outb = (const float*)d_in[5];

  char* ws = (char*)d_ws;
  size_t off = 0;
  auto alloc = [&](size_t bytes)->void*{
    void* p = ws + off; off += (bytes + 255) & ~(size_t)255; return p;
  };
  unsigned short* hid_bf  = (unsigned short*)alloc((size_t)M_TOTAL*HIDDEN*2);   // reused as ctx
  unsigned short* wqkv_bf = (unsigned short*)alloc((size_t)QKV_N*HIDDEN*2);
  unsigned short* outw_bf = (unsigned short*)alloc((size_t)HIDDEN*HIDDEN*2);
  unsigned short* qkv_bf  = (unsigned short*)alloc((size_t)M_TOTAL*QKV_N*2);    // reused as partials
  unsigned short* Qp      = (unsigned short*)alloc((size_t)BATCH*NHEADS*SEQ*QKS*2);
  unsigned short* Kp      = (unsigned short*)alloc((size_t)BATCH*NHEADS*SEQ*QKS*2);
  unsigned short* Vt      = (unsigned short*)alloc((size_t)BATCH*NHEADS*HEAD*SEQ*2);
  if (off > ws_size) return;

  unsigned short* pO  = qkv_bf;                                            // 47.2 MB
  float*          pML = (float*)(qkv_bf + (size_t)64*PART_SLOTS*128*HEAD); // 2.36 MB

  convert_f32_bf16<<<dim3(1024), dim3(256), 0, stream>>>(hid,  hid_bf,  M_TOTAL*HIDDEN/4);
  convert_f32_bf16<<<dim3(2048), dim3(256), 0, stream>>>(wqkv, wqkv_bf, QKV_N*HIDDEN/4);
  convert_f32_bf16<<<dim3(1024), dim3(256), 0, stream>>>(outw, outw_bf, HIDDEN*HIDDEN/4);

  gemm256<true><<<dim3(QKV_N/256, M_TOTAL/256), dim3(512), 0, stream>>>(
      hid_bf, wqkv_bf, bqkv, (void*)qkv_bf, M_TOTAL, QKV_N, HIDDEN);

  rope_scatter<<<dim3(BATCH*NHEADS*16), dim3(256), 0, stream>>>(qkv_bf, pos, Qp, Kp, Vt);

  unsigned short* ctx = hid_bf;  // hidden_bf dead after QKV GEMM
  attn_fd<<<dim3(2560), dim3(256), 0, stream>>>(Qp, Kp, Vt, ctx, pO, pML);
  attn_combine<<<dim3(64*12), dim3(256), 0, stream>>>(pO, pML, ctx);

  gemm256<false><<<dim3(HIDDEN/256, M_TOTAL/256), dim3(512), 0, stream>>>(
      ctx, outw_bf, outb, d_out, M_TOTAL, HIDDEN, HIDDEN);
}

// Round 15
// 478.161 us; speedup vs baseline: 1.1865x; 1.0097x over previous
//
#include <hip/hip_runtime.h>
#include <stdint.h>

#define HIDDEN  2560
#define NHEADS  32
#define HEAD    80
#define QKS     96           // Q/K padded head stride (3 x 32 for MFMA K)
#define SEQ     2048
#define BATCH   2
#define M_TOTAL (BATCH*SEQ)  // 4096
#define QKV_N   (3*HIDDEN)   // 7680
#define PART_SLOTS 36

typedef __attribute__((ext_vector_type(8))) short  short8;
typedef __attribute__((ext_vector_type(4))) float  floatx4;
typedef __attribute__((ext_vector_type(4))) float  fvec4;
typedef __attribute__((ext_vector_type(4))) unsigned short usvec4;
typedef __attribute__((ext_vector_type(2))) unsigned int uint2v;

#define SBAR() __builtin_amdgcn_sched_barrier(0)

__device__ __forceinline__ unsigned short f2bf(float x){
  union { float f; unsigned u; } v; v.f = x;
  unsigned r = v.u + 0x7fffu + ((v.u >> 16) & 1u);
  return (unsigned short)(r >> 16);
}
__device__ __forceinline__ float bf2f(unsigned short h){
  union { unsigned u; float f; } v; v.u = ((unsigned)h) << 16;
  return v.f;
}
__device__ __forceinline__ unsigned cvt_pk_bf16(float lo, float hi){
  unsigned r;
  asm volatile("v_cvt_pk_bf16_f32 %0, %1, %2" : "=v"(r) : "v"(lo), "v"(hi));
  return r;
}
__device__ __forceinline__ void gload16(const void* g, void* l){
  __builtin_amdgcn_global_load_lds(
    (const __attribute__((address_space(1))) void*)g,
    (__attribute__((address_space(3))) void*)l, 16, 0, 0);
}

// ---------------- f32 -> bf16 convert ----------------
__global__ __launch_bounds__(256)
void convert_f32_bf16(const float* __restrict__ src, unsigned short* __restrict__ dst, int n4){
  int idx = blockIdx.x*blockDim.x + threadIdx.x;
  int stride = gridDim.x*blockDim.x;
  for (int i = idx; i < n4; i += stride){
    fvec4 v = *(const fvec4*)(src + (size_t)i*4);
    usvec4 o;
    o[0]=f2bf(v[0]); o[1]=f2bf(v[1]); o[2]=f2bf(v[2]); o[3]=f2bf(v[3]);
    *(usvec4*)(dst + (size_t)i*4) = o;
  }
}

// ---------------- 256x256 GEMM, counted-vmcnt, compiler-interleaved --------
// (r11 configuration: best measured — 182 us QKV, MfmaUtil 39).
template<bool OUT_BF16>
__global__ __launch_bounds__(512, 2)
void gemm256(const unsigned short* __restrict__ A, const unsigned short* __restrict__ Bm,
             const float* __restrict__ bias, void* __restrict__ Cout,
             int M, int N, int K)
{
  __shared__ __align__(16) unsigned short lds[65536];   // 128 KB
  const int tid  = threadIdx.x;
  const int lane = tid & 63;
  const int w    = tid >> 6;          // wave 0..7
  const int wm   = w >> 2;            // 0..1
  const int wn   = w & 3;             // 0..3
  const int l15  = lane & 15, lg = lane >> 4;

  const int gx  = gridDim.x;
  const int lid = blockIdx.y*gx + blockIdx.x;
  const int nwg = gx*gridDim.y;
  const int qch = nwg >> 3;
  const int sl  = (lid & 7)*qch + (lid >> 3);
  const int bn0 = (sl % gx) * 256;
  const int bm0 = (sl / gx) * 256;

  const int nt = K >> 6;              // K-tiles of 64

  int rowq[2], cq[2];
  #pragma unroll
  for (int q=0;q<2;q++){
    int u = (w*2+q)*64 + lane;
    rowq[q] = u >> 2;
    cq[q]   = ((u & 3) - (rowq[q] >> 1)) & 3;
  }
  const int rot = (lg + (l15 >> 1)) & 3;   // read-side chunk rotation

  floatx4 acc[8][4];
  #pragma unroll
  for (int m=0;m<8;m++)
    #pragma unroll
    for (int n=0;n<4;n++) acc[m][n] = (floatx4)0.0f;

  auto STAGE = [&](int tau, int kkh){
    const int bufb = tau & 1;
    const size_t kofs = (size_t)tau*64 + kkh*32;
    const unsigned sA = (unsigned)(((bufb*2 + 0)*2 + kkh) * 8192);
    const unsigned sB = (unsigned)(((bufb*2 + 1)*2 + kkh) * 8192);
    #pragma unroll
    for (int q=0;q<2;q++){
      gload16(A  + (size_t)(bm0 + rowq[q])*K + kofs + cq[q]*8, &lds[sA + (w*2+q)*512]);
      gload16(Bm + (size_t)(bn0 + rowq[q])*K + kofs + cq[q]*8, &lds[sB + (w*2+q)*512]);
    }
  };
  auto COMPUTE = [&](int bufb, int kkh){
    const unsigned short* As = &lds[((bufb*2+0)*2+kkh)*8192];
    const unsigned short* Bs = &lds[((bufb*2+1)*2+kkh)*8192];
    short8 af[8], bfv[4];
    __builtin_amdgcn_s_setprio(1);
    #pragma unroll
    for (int n=0;n<4;n++)
      bfv[n] = *(const short8*)&Bs[(((wn*64 + n*16 + l15)<<2) + rot)*8];
    #pragma unroll
    for (int m=0;m<8;m++)
      af[m] = *(const short8*)&As[(((wm*128 + m*16 + l15)<<2) + rot)*8];
    #pragma unroll
    for (int m=0;m<8;m++)
      #pragma unroll
      for (int n=0;n<4;n++)
        acc[m][n] = __builtin_amdgcn_mfma_f32_16x16x32_bf16(af[m], bfv[n], acc[m][n], 0, 0, 0);
    __builtin_amdgcn_s_setprio(0);
  };

  // prologue: issue (0,kk0),(0,kk1),(1,kk0); oldest group landed at vmcnt(8)
  STAGE(0,0);
  STAGE(0,1);
  STAGE(1,0);
  asm volatile("s_waitcnt vmcnt(8)" ::: "memory");
  __builtin_amdgcn_s_barrier(); SBAR();

  for (int t=0; t<nt; ++t){
    const int c = t & 1;
    // ---- phase A: stage (t+1,kk1), compute kk0 ----
    if (t+1 < nt) STAGE(t+1, 1);
    COMPUTE(c, 0);
    if (t+1 < nt) asm volatile("s_waitcnt vmcnt(8)" ::: "memory");
    else          asm volatile("s_waitcnt vmcnt(0)" ::: "memory");
    __builtin_amdgcn_s_barrier(); SBAR();
    // ---- phase B: stage (t+2,kk0), compute kk1 ----
    if (t+2 < nt) STAGE(t+2, 0);
    COMPUTE(c, 1);
    if (t+1 < nt){
      if (t+2 < nt) asm volatile("s_waitcnt vmcnt(8)" ::: "memory");
      else          asm volatile("s_waitcnt vmcnt(4)" ::: "memory");
      __builtin_amdgcn_s_barrier(); SBAR();
    }
  }

  // epilogue
  #pragma unroll
  for (int m=0;m<8;m++){
    #pragma unroll
    for (int n=0;n<4;n++){
      int col = bn0 + wn*64 + n*16 + l15;
      float bs = bias[col];
      #pragma unroll
      for (int r=0;r<4;r++){
        int row = bm0 + wm*128 + m*16 + lg*4 + r;
        float v = acc[m][n][r] + bs;
        if (OUT_BF16) ((unsigned short*)Cout)[(size_t)row*N + col] = f2bf(v);
        else          ((float*)Cout)[(size_t)row*N + col] = v;
      }
    }
  }
}

// ---------------- RoPE + scatter to attention layouts ----------------
// qkv [B,S,7680] bf16 -> Qp,Kp [B,H,S,96] (rope d<32, zero d>=80), Vt [B,H,80,S]
__global__ __launch_bounds__(256)
void rope_scatter(const unsigned short* __restrict__ qkv,
                  const int* __restrict__ pos_ids,
                  unsigned short* __restrict__ Qp, unsigned short* __restrict__ Kp,
                  unsigned short* __restrict__ Vt)
{
  __shared__ float cosb[128*16];
  __shared__ float sinb[128*16];
  __shared__ __align__(16) unsigned short vtile[128*88];
  const int tid = threadIdx.x;
  const int blk = blockIdx.x;
  const int st = blk & 15, h = (blk >> 4) & 31, b = blk >> 9;
  const int s0 = st*128;

  for (int idx = tid; idx < 128*16; idx += 256){
    int sl = idx >> 4, i = idx & 15;
    float p = (float)pos_ids[b*SEQ + s0 + sl];
    float inv = exp2f(-(float)i * (13.287712379549449f/16.0f));
    float ang = p * inv;
    cosb[idx] = cosf(ang);
    sinb[idx] = sinf(ang);
  }
  __syncthreads();

  const size_t qkrow = (size_t)(b*SEQ + s0)*QKV_N;
  const size_t obase = ((size_t)(b*NHEADS + h)*SEQ + s0)*QKS;
  #pragma unroll
  for (int part = 0; part < 2; part++){
    const int cbase = part*HIDDEN + h*HEAD;
    unsigned short* outp = part ? Kp : Qp;
    for (int idx = tid; idx < 128*QKS; idx += 256){
      int sl = idx / QKS, d = idx - sl*QKS;
      const size_t rb = qkrow + (size_t)sl*QKV_N + cbase;
      float v;
      if (d < 16){
        float x1 = bf2f(qkv[rb + d]);
        float x2 = bf2f(qkv[rb + d + 16]);
        v = x1*cosb[sl*16 + d] - x2*sinb[sl*16 + d];
      } else if (d < 32){
        int i = d - 16;
        float x1 = bf2f(qkv[rb + d - 16]);
        float x2 = bf2f(qkv[rb + d]);
        v = x2*cosb[sl*16 + i] + x1*sinb[sl*16 + i];
      } else if (d < HEAD){
        v = bf2f(qkv[rb + d]);
      } else v = 0.0f;
      outp[obase + (size_t)sl*QKS + d] = f2bf(v);
    }
  }

  for (int idx = tid; idx < 128*HEAD; idx += 256){
    int sl = idx / HEAD, d = idx - sl*HEAD;
    vtile[sl*88 + d] = qkv[qkrow + (size_t)sl*QKV_N + 2*HIDDEN + h*HEAD + d];
  }
  __syncthreads();
  const size_t vtb = ((size_t)(b*NHEADS + h)*HEAD)*SEQ + s0;
  for (int idx = tid; idx < HEAD*128; idx += 256){
    int d = idx >> 7, sl = idx & 127;
    Vt[vtb + (size_t)d*SEQ + sl] = vtile[sl*88 + d];
  }
}

// ---------------- flash attention (causal, kv-split, double-buffered LDS) --
// block-task = (bh, 128-row q-tile, kv-part of <=8 key-tiles). 40 tasks/bh.
// T3-minimum 2-phase: STAGE(kt+1, buf^1) issued BEFORE compute(buf); single
// end-of-tile __syncthreads drains — stage latency hides under compute.
__global__ __launch_bounds__(256, 4)
void attn_fd(const unsigned short* __restrict__ Qp,
             const unsigned short* __restrict__ Kp,
             const unsigned short* __restrict__ Vt,
             unsigned short* __restrict__ ctx,
             unsigned short* __restrict__ pO,
             float* __restrict__ pML)
{
  __shared__ __align__(16) unsigned short Klds[2][64*96];  // 24 KB, swizzled
  __shared__ __align__(16) unsigned short Vlds[2][80*64];  // 20 KB, swizzled
  __shared__ __align__(16) unsigned short p_lds[4][32*36]; // 9.2 KB
  const int tid = threadIdx.x;
  const int lane = tid & 63, w = tid >> 6;
  const int l15 = lane & 15, lg = lane >> 4;

  const int bid = blockIdx.x;
  const int xcd = bid & 7, j = bid >> 3;     // j 0..319
  const int bh  = (j/40)*8 + xcd;
  const int tr  = j - (j/40)*40;

  int qt, part, np;
  if (tr < 16)      { qt = 12 + (tr>>2); part = tr & 3; np = 4; }
  else if (tr < 28) { int t = tr-16; int q3 = t/3; qt = 8 + q3; part = t - q3*3; np = 3; }
  else if (tr < 36) { int t = tr-28; qt = 4 + (t>>1); part = t & 1; np = 2; }
  else              { qt = tr - 36; part = 0; np = 1; }
  const int nk  = 2*qt + 2;
  const int kt0 = (part*nk)/np, kt1 = ((part+1)*nk)/np;
  const int q0  = qt*128 + w*32;

  const unsigned short* Qb = Qp + ((size_t)bh*SEQ)*QKS;
  const unsigned short* Kb = Kp + ((size_t)bh*SEQ)*QKS;
  const unsigned short* Vb = Vt + ((size_t)bh*HEAD)*SEQ;

  short8 qf[2][3];
  #pragma unroll
  for (int mi=0; mi<2; mi++)
    #pragma unroll
    for (int kc=0; kc<3; kc++)
      qf[mi][kc] = *(const short8*)&Qb[(size_t)(q0 + mi*16 + l15)*QKS + kc*32 + lg*8];

  int ksrow[3], ksc[3];
  #pragma unroll
  for (int t=0;t<3;t++){
    int ci = (w*3 + t)*64 + lane;       // K chunk 0..767
    int row = ci/12, c = ci - row*12;
    ksrow[t] = row;
    ksc[t]   = (c ^ (row & 3))*8;
  }
  int vsrow[3], vsc[3];
  #pragma unroll
  for (int t=0;t<3;t++){
    int i = w + 4*t;                    // V instr 0..9
    int row = i*8 + (lane >> 3), c = lane & 7;
    vsrow[t] = row;
    vsc[t]   = (c ^ (row & 7))*8;
  }

  auto STAGE_T = [&](int kt, int bb){
    #pragma unroll
    for (int t=0;t<3;t++)
      gload16(Kb + (size_t)(kt*64 + ksrow[t])*QKS + ksc[t], &Klds[bb][(w*3+t)*512]);
    #pragma unroll
    for (int t=0;t<3;t++){
      int i = w + 4*t;
      if (i < 10)
        gload16(Vb + (size_t)vsrow[t]*SEQ + kt*64 + vsc[t], &Vlds[bb][i*512]);
    }
  };

  float mrun[2] = {-3e38f, -3e38f};
  float lrun[2] = {0.0f, 0.0f};
  floatx4 oacc[2][5];
  #pragma unroll
  for (int mi=0;mi<2;mi++)
    #pragma unroll
    for (int di=0;di<5;di++) oacc[mi][di] = (floatx4)0.0f;

  const float SC = 0.1118033988749895f * 1.4426950408889634f; // 1/sqrt(80)*log2(e)

  // prologue: stage first tile, publish
  STAGE_T(kt0, 0);
  __syncthreads();   // compiler drains vmcnt(0) lgkmcnt(0) before barrier

  for (int kt = kt0; kt < kt1; kt++){
    const int cur = (kt - kt0) & 1;
    // issue next tile into the other buffer (its last readers finished
    // before the barrier that ended iteration kt-1 -> race-free)
    if (kt+1 < kt1) STAGE_T(kt+1, cur^1);

    if (kt*64 <= q0 + 31){
      floatx4 sacc[2][4];
      #pragma unroll
      for (int mi=0;mi<2;mi++)
        #pragma unroll
        for (int ni=0;ni<4;ni++) sacc[mi][ni] = (floatx4)0.0f;

      __builtin_amdgcn_s_setprio(1);
      #pragma unroll
      for (int kc=0; kc<3; kc++){
        short8 kf[4];
        #pragma unroll
        for (int ni=0; ni<4; ni++){
          int r = ni*16 + l15;
          kf[ni] = *(const short8*)&Klds[cur][r*96 + (((kc*4+lg) ^ (r & 3))<<3)];
        }
        #pragma unroll
        for (int mi=0; mi<2; mi++)
          #pragma unroll
          for (int ni=0; ni<4; ni++)
            sacc[mi][ni] = __builtin_amdgcn_mfma_f32_16x16x32_bf16(kf[ni], qf[mi][kc], sacc[mi][ni], 0, 0, 0);
      }
      __builtin_amdgcn_s_setprio(0);

      if (kt*64 + 63 > q0){
        #pragma unroll
        for (int mi=0; mi<2; mi++){
          int qrow = q0 + mi*16 + l15;
          #pragma unroll
          for (int ni=0; ni<4; ni++){
            int kb = kt*64 + ni*16 + lg*4;
            #pragma unroll
            for (int r=0; r<4; r++)
              if (kb + r > qrow) sacc[mi][ni][r] = -3e38f;
          }
        }
      }

      #pragma unroll
      for (int mi=0; mi<2; mi++){
        float pm = -3e38f;
        #pragma unroll
        for (int ni=0; ni<4; ni++)
          #pragma unroll
          for (int r=0; r<4; r++) pm = fmaxf(pm, sacc[mi][ni][r]);
        pm = fmaxf(pm, __shfl_xor(pm, 16));
        pm = fmaxf(pm, __shfl_xor(pm, 32));
        float mold = mrun[mi];
        float mnew = fmaxf(mold, pm);
        float msc  = mnew*SC;
        float alpha = __builtin_amdgcn_exp2f(mold*SC - msc);
        float rs = 0.0f;
        #pragma unroll
        for (int ni=0; ni<4; ni++)
          #pragma unroll
          for (int r=0; r<4; r++){
            float p = __builtin_amdgcn_exp2f(sacc[mi][ni][r]*SC - msc);
            sacc[mi][ni][r] = p;
            rs += p;
          }
        rs += __shfl_xor(rs, 16);
        rs += __shfl_xor(rs, 32);
        lrun[mi] = lrun[mi]*alpha + rs;
        mrun[mi] = mnew;
        #pragma unroll
        for (int di=0; di<5; di++) oacc[mi][di] *= alpha;
      }

      #pragma unroll
      for (int kk=0; kk<2; kk++){
        #pragma unroll
        for (int mi=0; mi<2; mi++)
          #pragma unroll
          for (int nl=0; nl<2; nl++){
            int ni = kk*2 + nl;
            uint2v pk;
            pk[0] = cvt_pk_bf16(sacc[mi][ni][0], sacc[mi][ni][1]);
            pk[1] = cvt_pk_bf16(sacc[mi][ni][2], sacc[mi][ni][3]);
            *(uint2v*)&p_lds[w][(mi*16 + l15)*36 + nl*16 + lg*4] = pk;
          }
        __builtin_amdgcn_s_setprio(1);
        short8 pa[2];
        #pragma unroll
        for (int mi=0;mi<2;mi++)
          pa[mi] = *(const short8*)&p_lds[w][(mi*16 + l15)*36 + lg*8];
        #pragma unroll
        for (int di=0; di<5; di++){
          int r = di*16 + l15;
          short8 vf = *(const short8*)&Vlds[cur][r*64 + (((kk*4+lg) ^ (r & 7))<<3)];
          #pragma unroll
          for (int mi=0;mi<2;mi++)
            oacc[mi][di] = __builtin_amdgcn_mfma_f32_16x16x32_bf16(vf, pa[mi], oacc[mi][di], 0, 0, 0);
        }
        __builtin_amdgcn_s_setprio(0);
      }
    }
    __syncthreads();   // drains this tile's reads + next tile's stage writes
  }

  const int b = bh >> 5, h = bh & 31;
  if (np == 1){
    #pragma unroll
    for (int mi=0;mi<2;mi++){
      float inv = 1.0f/lrun[mi];
      size_t crow = ((size_t)(b*SEQ + q0 + mi*16 + l15))*HIDDEN + h*HEAD;
      #pragma unroll
      for (int di=0;di<5;di++){
        uint2v pk;
        pk[0] = cvt_pk_bf16(oacc[mi][di][0]*inv, oacc[mi][di][1]*inv);
        pk[1] = cvt_pk_bf16(oacc[mi][di][2]*inv, oacc[mi][di][3]*inv);
        *(uint2v*)&ctx[crow + di*16 + lg*4] = pk;
      }
    }
  } else {
    int base;
    if (np == 2)      base = (qt-4)*2;
    else if (np == 3) base = 8 + (qt-8)*3;
    else              base = 20 + (qt-12)*4;
    const int pslot = bh*PART_SLOTS + base + part;
    unsigned short* Ob = pO + (size_t)pslot*128*HEAD;
    #pragma unroll
    for (int mi=0;mi<2;mi++){
      int grow = w*32 + mi*16 + l15;
      #pragma unroll
      for (int di=0;di<5;di++){
        uint2v pk;
        pk[0] = cvt_pk_bf16(oacc[mi][di][0], oacc[mi][di][1]);
        pk[1] = cvt_pk_bf16(oacc[mi][di][2], oacc[mi][di][3]);
        *(uint2v*)&Ob[grow*HEAD + di*16 + lg*4] = pk;
      }
      if (lg == 0){
        float* mlb = pML + ((size_t)pslot*128 + grow)*2;
        mlb[0] = mrun[mi];
        mlb[1] = lrun[mi];
      }
    }
  }
}

// ---------------- combine partials (coalesced flat-tile reads) ----------------
__global__ __launch_bounds__(256)
void attn_combine(const unsigned short* __restrict__ pO, const float* __restrict__ pML,
                  unsigned short* __restrict__ ctx)
{
  const int bid = blockIdx.x;              // 64*12
  const int bh = bid / 12, qt = 4 + (bid - (bid/12)*12);
  int base, np;
  if (qt < 8)       { base = (qt-4)*2;       np = 2; }
  else if (qt < 12) { base = 8 + (qt-8)*3;   np = 3; }
  else              { base = 20 + (qt-12)*4; np = 4; }
  const int slot0 = bh*PART_SLOTS + base;
  const float SC = 0.1118033988749895f * 1.4426950408889634f;
  const int b = bh >> 5, h = bh & 31;

  #pragma unroll
  for (int c = 0; c < 5; c++){
    const int e   = c*2048 + threadIdx.x*8;   // element in flat 128x80 tile
    const int row = e / 80, d = e - row*80;   // 80%8==0: never crosses rows

    float m[4], l[4], ms = -3e38f;
    for (int p=0;p<np;p++){
      const float* mlb = pML + ((size_t)(slot0+p)*128 + row)*2;
      m[p] = mlb[0]; l[p] = mlb[1];
      ms = fmaxf(ms, m[p]);
    }
    float wgt[4], lsum = 0.0f;
    for (int p=0;p<np;p++){
      wgt[p] = exp2f((m[p]-ms)*SC);
      lsum += wgt[p]*l[p];
    }
    const float inv = 1.0f/lsum;

    float acc[8] = {0,0,0,0,0,0,0,0};
    for (int p=0;p<np;p++){
      short8 v = *(const short8*)&pO[(size_t)(slot0+p)*128*HEAD + e];
      #pragma unroll
      for (int j=0;j<8;j++) acc[j] += wgt[p]*bf2f((unsigned short)v[j]);
    }
    short8 o;
    #pragma unroll
    for (int j=0;j<8;j++) o[j] = (short)f2bf(acc[j]*inv);
    *(short8*)&ctx[((size_t)(b*SEQ + qt*128 + row))*HIDDEN + h*HEAD + d] = o;
  }
}

// ---------------- launch ----------------
extern "C" void kernel_launch(void* const* d_in, const int* in_sizes, int n_in,
                              void* d_out, int out_size, void* d_ws, size_t ws_size,
                              hipStream_t stream)
{
  const int*   pos  = (const int*)  d_in[0];
  const float* hid  = (const float*)d_in[1];
  const float* wqkv = (const float*)d_in[2];
  const float* bqkv = (const float*)d_in[3];
  const float* outw = (const float*)d_in[4];
  const float* outb = (const float*)d_in[5];

  char* ws = (char*)d_ws;
  size_t off = 0;
  auto alloc = [&](size_t bytes)->void*{
    void* p = ws + off; off += (bytes + 255) & ~(size_t)255; return p;
  };
  unsigned short* hid_bf  = (unsigned short*)alloc((size_t)M_TOTAL*HIDDEN*2);   // reused as ctx
  unsigned short* wqkv_bf = (unsigned short*)alloc((size_t)QKV_N*HIDDEN*2);
  unsigned short* outw_bf = (unsigned short*)alloc((size_t)HIDDEN*HIDDEN*2);
  unsigned short* qkv_bf  = (unsigned short*)alloc((size_t)M_TOTAL*QKV_N*2);    // reused as partials
  unsigned short* Qp      = (unsigned short*)alloc((size_t)BATCH*NHEADS*SEQ*QKS*2);
  unsigned short* Kp      = (unsigned short*)alloc((size_t)BATCH*NHEADS*SEQ*QKS*2);
  unsigned short* Vt      = (unsigned short*)alloc((size_t)BATCH*NHEADS*HEAD*SEQ*2);
  if (off > ws_size) return;

  unsigned short* pO  = qkv_bf;                                            // 47.2 MB
  float*          pML = (float*)(qkv_bf + (size_t)64*PART_SLOTS*128*HEAD); // 2.36 MB

  convert_f32_bf16<<<dim3(1024), dim3(256), 0, stream>>>(hid,  hid_bf,  M_TOTAL*HIDDEN/4);
  convert_f32_bf16<<<dim3(2048), dim3(256), 0, stream>>>(wqkv, wqkv_bf, QKV_N*HIDDEN/4);
  convert_f32_bf16<<<dim3(1024), dim3(256), 0, stream>>>(outw, outw_bf, HIDDEN*HIDDEN/4);

  gemm256<true><<<dim3(QKV_N/256, M_TOTAL/256), dim3(512), 0, stream>>>(
      hid_bf, wqkv_bf, bqkv, (void*)qkv_bf, M_TOTAL, QKV_N, HIDDEN);

  rope_scatter<<<dim3(BATCH*NHEADS*16), dim3(256), 0, stream>>>(qkv_bf, pos, Qp, Kp, Vt);

  unsigned short* ctx = hid_bf;  // hidden_bf dead after QKV GEMM
  attn_fd<<<dim3(2560), dim3(256), 0, stream>>>(Qp, Kp, Vt, ctx, pO, pML);
  attn_combine<<<dim3(64*12), dim3(256), 0, stream>>>(pO, pML, ctx);

  gemm256<false><<<dim3(HIDDEN/256, M_TOTAL/256), dim3(512), 0, stream>>>(
      ctx, outw_bf, outb, d_out, M_TOTAL, HIDDEN, HIDDEN);
}

// Round 16
// 473.996 us; speedup vs baseline: 1.1969x; 1.0088x over previous
//
#include <hip/hip_runtime.h>
#include <stdint.h>

#define HIDDEN  2560
#define NHEADS  32
#define HEAD    80
#define QKS     96           // Q/K padded head stride (3 x 32 for MFMA K)
#define SEQ     2048
#define BATCH   2
#define M_TOTAL (BATCH*SEQ)  // 4096
#define QKV_N   (3*HIDDEN)   // 7680
#define PART_SLOTS 36

typedef __attribute__((ext_vector_type(8))) short  short8;
typedef __attribute__((ext_vector_type(4))) float  floatx4;
typedef __attribute__((ext_vector_type(4))) float  fvec4;
typedef __attribute__((ext_vector_type(4))) unsigned short usvec4;
typedef __attribute__((ext_vector_type(2))) unsigned int uint2v;

#define SBAR() __builtin_amdgcn_sched_barrier(0)

__device__ __forceinline__ unsigned short f2bf(float x){
  union { float f; unsigned u; } v; v.f = x;
  unsigned r = v.u + 0x7fffu + ((v.u >> 16) & 1u);
  return (unsigned short)(r >> 16);
}
__device__ __forceinline__ float bf2f(unsigned short h){
  union { unsigned u; float f; } v; v.u = ((unsigned)h) << 16;
  return v.f;
}
__device__ __forceinline__ unsigned cvt_pk_bf16(float lo, float hi){
  unsigned r;
  asm volatile("v_cvt_pk_bf16_f32 %0, %1, %2" : "=v"(r) : "v"(lo), "v"(hi));
  return r;
}
__device__ __forceinline__ void gload16(const void* g, void* l){
  __builtin_amdgcn_global_load_lds(
    (const __attribute__((address_space(1))) void*)g,
    (__attribute__((address_space(3))) void*)l, 16, 0, 0);
}

// ---------------- f32 -> bf16 convert ----------------
__global__ __launch_bounds__(256)
void convert_f32_bf16(const float* __restrict__ src, unsigned short* __restrict__ dst, int n4){
  int idx = blockIdx.x*blockDim.x + threadIdx.x;
  int stride = gridDim.x*blockDim.x;
  for (int i = idx; i < n4; i += stride){
    fvec4 v = *(const fvec4*)(src + (size_t)i*4);
    usvec4 o;
    o[0]=f2bf(v[0]); o[1]=f2bf(v[1]); o[2]=f2bf(v[2]); o[3]=f2bf(v[3]);
    *(usvec4*)(dst + (size_t)i*4) = o;
  }
}

// ---------------- 256x256 GEMM, counted-vmcnt, compiler-interleaved --------
// (r11 configuration: best measured — 182 us QKV, MfmaUtil 39).
template<bool OUT_BF16>
__global__ __launch_bounds__(512, 2)
void gemm256(const unsigned short* __restrict__ A, const unsigned short* __restrict__ Bm,
             const float* __restrict__ bias, void* __restrict__ Cout,
             int M, int N, int K)
{
  __shared__ __align__(16) unsigned short lds[65536];   // 128 KB
  const int tid  = threadIdx.x;
  const int lane = tid & 63;
  const int w    = tid >> 6;          // wave 0..7
  const int wm   = w >> 2;            // 0..1
  const int wn   = w & 3;             // 0..3
  const int l15  = lane & 15, lg = lane >> 4;

  const int gx  = gridDim.x;
  const int lid = blockIdx.y*gx + blockIdx.x;
  const int nwg = gx*gridDim.y;
  const int qch = nwg >> 3;
  const int sl  = (lid & 7)*qch + (lid >> 3);
  const int bn0 = (sl % gx) * 256;
  const int bm0 = (sl / gx) * 256;

  const int nt = K >> 6;              // K-tiles of 64

  int rowq[2], cq[2];
  #pragma unroll
  for (int q=0;q<2;q++){
    int u = (w*2+q)*64 + lane;
    rowq[q] = u >> 2;
    cq[q]   = ((u & 3) - (rowq[q] >> 1)) & 3;
  }
  const int rot = (lg + (l15 >> 1)) & 3;   // read-side chunk rotation

  floatx4 acc[8][4];
  #pragma unroll
  for (int m=0;m<8;m++)
    #pragma unroll
    for (int n=0;n<4;n++) acc[m][n] = (floatx4)0.0f;

  auto STAGE = [&](int tau, int kkh){
    const int bufb = tau & 1;
    const size_t kofs = (size_t)tau*64 + kkh*32;
    const unsigned sA = (unsigned)(((bufb*2 + 0)*2 + kkh) * 8192);
    const unsigned sB = (unsigned)(((bufb*2 + 1)*2 + kkh) * 8192);
    #pragma unroll
    for (int q=0;q<2;q++){
      gload16(A  + (size_t)(bm0 + rowq[q])*K + kofs + cq[q]*8, &lds[sA + (w*2+q)*512]);
      gload16(Bm + (size_t)(bn0 + rowq[q])*K + kofs + cq[q]*8, &lds[sB + (w*2+q)*512]);
    }
  };
  auto COMPUTE = [&](int bufb, int kkh){
    const unsigned short* As = &lds[((bufb*2+0)*2+kkh)*8192];
    const unsigned short* Bs = &lds[((bufb*2+1)*2+kkh)*8192];
    short8 af[8], bfv[4];
    __builtin_amdgcn_s_setprio(1);
    #pragma unroll
    for (int n=0;n<4;n++)
      bfv[n] = *(const short8*)&Bs[(((wn*64 + n*16 + l15)<<2) + rot)*8];
    #pragma unroll
    for (int m=0;m<8;m++)
      af[m] = *(const short8*)&As[(((wm*128 + m*16 + l15)<<2) + rot)*8];
    #pragma unroll
    for (int m=0;m<8;m++)
      #pragma unroll
      for (int n=0;n<4;n++)
        acc[m][n] = __builtin_amdgcn_mfma_f32_16x16x32_bf16(af[m], bfv[n], acc[m][n], 0, 0, 0);
    __builtin_amdgcn_s_setprio(0);
  };

  // prologue: issue (0,kk0),(0,kk1),(1,kk0); oldest group landed at vmcnt(8)
  STAGE(0,0);
  STAGE(0,1);
  STAGE(1,0);
  asm volatile("s_waitcnt vmcnt(8)" ::: "memory");
  __builtin_amdgcn_s_barrier(); SBAR();

  for (int t=0; t<nt; ++t){
    const int c = t & 1;
    // ---- phase A: stage (t+1,kk1), compute kk0 ----
    if (t+1 < nt) STAGE(t+1, 1);
    COMPUTE(c, 0);
    if (t+1 < nt) asm volatile("s_waitcnt vmcnt(8)" ::: "memory");
    else          asm volatile("s_waitcnt vmcnt(0)" ::: "memory");
    __builtin_amdgcn_s_barrier(); SBAR();
    // ---- phase B: stage (t+2,kk0), compute kk1 ----
    if (t+2 < nt) STAGE(t+2, 0);
    COMPUTE(c, 1);
    if (t+1 < nt){
      if (t+2 < nt) asm volatile("s_waitcnt vmcnt(8)" ::: "memory");
      else          asm volatile("s_waitcnt vmcnt(4)" ::: "memory");
      __builtin_amdgcn_s_barrier(); SBAR();
    }
  }

  // epilogue
  #pragma unroll
  for (int m=0;m<8;m++){
    #pragma unroll
    for (int n=0;n<4;n++){
      int col = bn0 + wn*64 + n*16 + l15;
      float bs = bias[col];
      #pragma unroll
      for (int r=0;r<4;r++){
        int row = bm0 + wm*128 + m*16 + lg*4 + r;
        float v = acc[m][n][r] + bs;
        if (OUT_BF16) ((unsigned short*)Cout)[(size_t)row*N + col] = f2bf(v);
        else          ((float*)Cout)[(size_t)row*N + col] = v;
      }
    }
  }
}

// ---------------- RoPE + scatter to attention layouts ----------------
// qkv [B,S,7680] bf16 -> Qp,Kp [B,H,S,96] (rope d<32, zero d>=80), Vt [B,H,80,S]
__global__ __launch_bounds__(256)
void rope_scatter(const unsigned short* __restrict__ qkv,
                  const int* __restrict__ pos_ids,
                  unsigned short* __restrict__ Qp, unsigned short* __restrict__ Kp,
                  unsigned short* __restrict__ Vt)
{
  __shared__ float cosb[128*16];
  __shared__ float sinb[128*16];
  __shared__ __align__(16) unsigned short vtile[128*88];
  const int tid = threadIdx.x;
  const int blk = blockIdx.x;
  const int st = blk & 15, h = (blk >> 4) & 31, b = blk >> 9;
  const int s0 = st*128;

  for (int idx = tid; idx < 128*16; idx += 256){
    int sl = idx >> 4, i = idx & 15;
    float p = (float)pos_ids[b*SEQ + s0 + sl];
    float inv = exp2f(-(float)i * (13.287712379549449f/16.0f));
    float ang = p * inv;
    cosb[idx] = cosf(ang);
    sinb[idx] = sinf(ang);
  }
  __syncthreads();

  const size_t qkrow = (size_t)(b*SEQ + s0)*QKV_N;
  const size_t obase = ((size_t)(b*NHEADS + h)*SEQ + s0)*QKS;
  #pragma unroll
  for (int part = 0; part < 2; part++){
    const int cbase = part*HIDDEN + h*HEAD;
    unsigned short* outp = part ? Kp : Qp;
    for (int idx = tid; idx < 128*QKS; idx += 256){
      int sl = idx / QKS, d = idx - sl*QKS;
      const size_t rb = qkrow + (size_t)sl*QKV_N + cbase;
      float v;
      if (d < 16){
        float x1 = bf2f(qkv[rb + d]);
        float x2 = bf2f(qkv[rb + d + 16]);
        v = x1*cosb[sl*16 + d] - x2*sinb[sl*16 + d];
      } else if (d < 32){
        int i = d - 16;
        float x1 = bf2f(qkv[rb + d - 16]);
        float x2 = bf2f(qkv[rb + d]);
        v = x2*cosb[sl*16 + i] + x1*sinb[sl*16 + i];
      } else if (d < HEAD){
        v = bf2f(qkv[rb + d]);
      } else v = 0.0f;
      outp[obase + (size_t)sl*QKS + d] = f2bf(v);
    }
  }

  for (int idx = tid; idx < 128*HEAD; idx += 256){
    int sl = idx / HEAD, d = idx - sl*HEAD;
    vtile[sl*88 + d] = qkv[qkrow + (size_t)sl*QKV_N + 2*HIDDEN + h*HEAD + d];
  }
  __syncthreads();
  const size_t vtb = ((size_t)(b*NHEADS + h)*HEAD)*SEQ + s0;
  for (int idx = tid; idx < HEAD*128; idx += 256){
    int d = idx >> 7, sl = idx & 127;
    Vt[vtb + (size_t)d*SEQ + sl] = vtile[sl*88 + d];
  }
}

// ---------------- flash attention (causal, kv-split, double-buffered LDS) --
// block-task = (bh, 128-row q-tile, kv-part of <=8 key-tiles). 40 tasks/bh.
// T3-minimum 2-phase: STAGE(kt+1, buf^1) issued BEFORE compute(buf); single
// end-of-tile __syncthreads drains — stage latency hides under compute.
__global__ __launch_bounds__(256, 4)
void attn_fd(const unsigned short* __restrict__ Qp,
             const unsigned short* __restrict__ Kp,
             const unsigned short* __restrict__ Vt,
             unsigned short* __restrict__ ctx,
             unsigned short* __restrict__ pO,
             float* __restrict__ pML)
{
  __shared__ __align__(16) unsigned short Klds[2][64*96];  // 24 KB, swizzled
  __shared__ __align__(16) unsigned short Vlds[2][80*64];  // 20 KB, swizzled
  __shared__ __align__(16) unsigned short p_lds[4][32*36]; // 9.2 KB
  const int tid = threadIdx.x;
  const int lane = tid & 63, w = tid >> 6;
  const int l15 = lane & 15, lg = lane >> 4;

  const int bid = blockIdx.x;
  const int xcd = bid & 7, j = bid >> 3;     // j 0..319
  const int bh  = (j/40)*8 + xcd;
  const int tr  = j - (j/40)*40;

  int qt, part, np;
  if (tr < 16)      { qt = 12 + (tr>>2); part = tr & 3; np = 4; }
  else if (tr < 28) { int t = tr-16; int q3 = t/3; qt = 8 + q3; part = t - q3*3; np = 3; }
  else if (tr < 36) { int t = tr-28; qt = 4 + (t>>1); part = t & 1; np = 2; }
  else              { qt = tr - 36; part = 0; np = 1; }
  const int nk  = 2*qt + 2;
  const int kt0 = (part*nk)/np, kt1 = ((part+1)*nk)/np;
  const int q0  = qt*128 + w*32;

  const unsigned short* Qb = Qp + ((size_t)bh*SEQ)*QKS;
  const unsigned short* Kb = Kp + ((size_t)bh*SEQ)*QKS;
  const unsigned short* Vb = Vt + ((size_t)bh*HEAD)*SEQ;

  short8 qf[2][3];
  #pragma unroll
  for (int mi=0; mi<2; mi++)
    #pragma unroll
    for (int kc=0; kc<3; kc++)
      qf[mi][kc] = *(const short8*)&Qb[(size_t)(q0 + mi*16 + l15)*QKS + kc*32 + lg*8];

  int ksrow[3], ksc[3];
  #pragma unroll
  for (int t=0;t<3;t++){
    int ci = (w*3 + t)*64 + lane;       // K chunk 0..767
    int row = ci/12, c = ci - row*12;
    ksrow[t] = row;
    ksc[t]   = (c ^ (row & 3))*8;
  }
  int vsrow[3], vsc[3];
  #pragma unroll
  for (int t=0;t<3;t++){
    int i = w + 4*t;                    // V instr 0..9
    int row = i*8 + (lane >> 3), c = lane & 7;
    vsrow[t] = row;
    vsc[t]   = (c ^ (row & 7))*8;
  }

  auto STAGE_T = [&](int kt, int bb){
    #pragma unroll
    for (int t=0;t<3;t++)
      gload16(Kb + (size_t)(kt*64 + ksrow[t])*QKS + ksc[t], &Klds[bb][(w*3+t)*512]);
    #pragma unroll
    for (int t=0;t<3;t++){
      int i = w + 4*t;
      if (i < 10)
        gload16(Vb + (size_t)vsrow[t]*SEQ + kt*64 + vsc[t], &Vlds[bb][i*512]);
    }
  };

  float mrun[2] = {-3e38f, -3e38f};
  float lrun[2] = {0.0f, 0.0f};
  floatx4 oacc[2][5];
  #pragma unroll
  for (int mi=0;mi<2;mi++)
    #pragma unroll
    for (int di=0;di<5;di++) oacc[mi][di] = (floatx4)0.0f;

  const float SC = 0.1118033988749895f * 1.4426950408889634f; // 1/sqrt(80)*log2(e)

  // prologue: stage first tile, publish
  STAGE_T(kt0, 0);
  __syncthreads();   // compiler drains vmcnt(0) lgkmcnt(0) before barrier

  for (int kt = kt0; kt < kt1; kt++){
    const int cur = (kt - kt0) & 1;
    // issue next tile into the other buffer (its last readers finished
    // before the barrier that ended iteration kt-1 -> race-free)
    if (kt+1 < kt1) STAGE_T(kt+1, cur^1);

    if (kt*64 <= q0 + 31){
      floatx4 sacc[2][4];
      #pragma unroll
      for (int mi=0;mi<2;mi++)
        #pragma unroll
        for (int ni=0;ni<4;ni++) sacc[mi][ni] = (floatx4)0.0f;

      __builtin_amdgcn_s_setprio(1);
      #pragma unroll
      for (int kc=0; kc<3; kc++){
        short8 kf[4];
        #pragma unroll
        for (int ni=0; ni<4; ni++){
          int r = ni*16 + l15;
          kf[ni] = *(const short8*)&Klds[cur][r*96 + (((kc*4+lg) ^ (r & 3))<<3)];
        }
        #pragma unroll
        for (int mi=0; mi<2; mi++)
          #pragma unroll
          for (int ni=0; ni<4; ni++)
            sacc[mi][ni] = __builtin_amdgcn_mfma_f32_16x16x32_bf16(kf[ni], qf[mi][kc], sacc[mi][ni], 0, 0, 0);
      }
      __builtin_amdgcn_s_setprio(0);

      if (kt*64 + 63 > q0){
        #pragma unroll
        for (int mi=0; mi<2; mi++){
          int qrow = q0 + mi*16 + l15;
          #pragma unroll
          for (int ni=0; ni<4; ni++){
            int kb = kt*64 + ni*16 + lg*4;
            #pragma unroll
            for (int r=0; r<4; r++)
              if (kb + r > qrow) sacc[mi][ni][r] = -3e38f;
          }
        }
      }

      #pragma unroll
      for (int mi=0; mi<2; mi++){
        float pm = -3e38f;
        #pragma unroll
        for (int ni=0; ni<4; ni++)
          #pragma unroll
          for (int r=0; r<4; r++) pm = fmaxf(pm, sacc[mi][ni][r]);
        pm = fmaxf(pm, __shfl_xor(pm, 16));
        pm = fmaxf(pm, __shfl_xor(pm, 32));
        float mold = mrun[mi];
        float mnew = fmaxf(mold, pm);
        float msc  = mnew*SC;
        float alpha = __builtin_amdgcn_exp2f(mold*SC - msc);
        float rs = 0.0f;
        #pragma unroll
        for (int ni=0; ni<4; ni++)
          #pragma unroll
          for (int r=0; r<4; r++){
            float p = __builtin_amdgcn_exp2f(sacc[mi][ni][r]*SC - msc);
            sacc[mi][ni][r] = p;
            rs += p;
          }
        rs += __shfl_xor(rs, 16);
        rs += __shfl_xor(rs, 32);
        lrun[mi] = lrun[mi]*alpha + rs;
        mrun[mi] = mnew;
        #pragma unroll
        for (int di=0; di<5; di++) oacc[mi][di] *= alpha;
      }

      #pragma unroll
      for (int kk=0; kk<2; kk++){
        #pragma unroll
        for (int mi=0; mi<2; mi++)
          #pragma unroll
          for (int nl=0; nl<2; nl++){
            int ni = kk*2 + nl;
            uint2v pk;
            pk[0] = cvt_pk_bf16(sacc[mi][ni][0], sacc[mi][ni][1]);
            pk[1] = cvt_pk_bf16(sacc[mi][ni][2], sacc[mi][ni][3]);
            *(uint2v*)&p_lds[w][(mi*16 + l15)*36 + nl*16 + lg*4] = pk;
          }
        __builtin_amdgcn_s_setprio(1);
        short8 pa[2];
        #pragma unroll
        for (int mi=0;mi<2;mi++)
          pa[mi] = *(const short8*)&p_lds[w][(mi*16 + l15)*36 + lg*8];
        #pragma unroll
        for (int di=0; di<5; di++){
          int r = di*16 + l15;
          short8 vf = *(const short8*)&Vlds[cur][r*64 + (((kk*4+lg) ^ (r & 7))<<3)];
          #pragma unroll
          for (int mi=0;mi<2;mi++)
            oacc[mi][di] = __builtin_amdgcn_mfma_f32_16x16x32_bf16(vf, pa[mi], oacc[mi][di], 0, 0, 0);
        }
        __builtin_amdgcn_s_setprio(0);
      }
    }
    __syncthreads();   // drains this tile's reads + next tile's stage writes
  }

  const int b = bh >> 5, h = bh & 31;
  if (np == 1){
    #pragma unroll
    for (int mi=0;mi<2;mi++){
      float inv = 1.0f/lrun[mi];
      size_t crow = ((size_t)(b*SEQ + q0 + mi*16 + l15))*HIDDEN + h*HEAD;
      #pragma unroll
      for (int di=0;di<5;di++){
        uint2v pk;
        pk[0] = cvt_pk_bf16(oacc[mi][di][0]*inv, oacc[mi][di][1]*inv);
        pk[1] = cvt_pk_bf16(oacc[mi][di][2]*inv, oacc[mi][di][3]*inv);
        *(uint2v*)&ctx[crow + di*16 + lg*4] = pk;
      }
    }
  } else {
    int base;
    if (np == 2)      base = (qt-4)*2;
    else if (np == 3) base = 8 + (qt-8)*3;
    else              base = 20 + (qt-12)*4;
    const int pslot = bh*PART_SLOTS + base + part;
    unsigned short* Ob = pO + (size_t)pslot*128*HEAD;
    #pragma unroll
    for (int mi=0;mi<2;mi++){
      int grow = w*32 + mi*16 + l15;
      #pragma unroll
      for (int di=0;di<5;di++){
        uint2v pk;
        pk[0] = cvt_pk_bf16(oacc[mi][di][0], oacc[mi][di][1]);
        pk[1] = cvt_pk_bf16(oacc[mi][di][2], oacc[mi][di][3]);
        *(uint2v*)&Ob[grow*HEAD + di*16 + lg*4] = pk;
      }
      if (lg == 0){
        float* mlb = pML + ((size_t)pslot*128 + grow)*2;
        mlb[0] = mrun[mi];
        mlb[1] = lrun[mi];
      }
    }
  }
}

// ---------------- combine partials (coalesced flat-tile reads) ----------------
__global__ __launch_bounds__(256)
void attn_combine(const unsigned short* __restrict__ pO, const float* __restrict__ pML,
                  unsigned short* __restrict__ ctx)
{
  const int bid = blockIdx.x;              // 64*12
  const int bh = bid / 12, qt = 4 + (bid - (bid/12)*12);
  int base, np;
  if (qt < 8)       { base = (qt-4)*2;       np = 2; }
  else if (qt < 12) { base = 8 + (qt-8)*3;   np = 3; }
  else              { base = 20 + (qt-12)*4; np = 4; }
  const int slot0 = bh*PART_SLOTS + base;
  const float SC = 0.1118033988749895f * 1.4426950408889634f;
  const int b = bh >> 5, h = bh & 31;

  #pragma unroll
  for (int c = 0; c < 5; c++){
    const int e   = c*2048 + threadIdx.x*8;   // element in flat 128x80 tile
    const int row = e / 80, d = e - row*80;   // 80%8==0: never crosses rows

    float m[4], l[4], ms = -3e38f;
    for (int p=0;p<np;p++){
      const float* mlb = pML + ((size_t)(slot0+p)*128 + row)*2;
      m[p] = mlb[0]; l[p] = mlb[1];
      ms = fmaxf(ms, m[p]);
    }
    float wgt[4], lsum = 0.0f;
    for (int p=0;p<np;p++){
      wgt[p] = exp2f((m[p]-ms)*SC);
      lsum += wgt[p]*l[p];
    }
    const float inv = 1.0f/lsum;

    float acc[8] = {0,0,0,0,0,0,0,0};
    for (int p=0;p<np;p++){
      short8 v = *(const short8*)&pO[(size_t)(slot0+p)*128*HEAD + e];
      #pragma unroll
      for (int j=0;j<8;j++) acc[j] += wgt[p]*bf2f((unsigned short)v[j]);
    }
    short8 o;
    #pragma unroll
    for (int j=0;j<8;j++) o[j] = (short)f2bf(acc[j]*inv);
    *(short8*)&ctx[((size_t)(b*SEQ + qt*128 + row))*HIDDEN + h*HEAD + d] = o;
  }
}

// ---------------- launch ----------------
extern "C" void kernel_launch(void* const* d_in, const int* in_sizes, int n_in,
                              void* d_out, int out_size, void* d_ws, size_t ws_size,
                              hipStream_t stream)
{
  const int*   pos  = (const int*)  d_in[0];
  const float* hid  = (const float*)d_in[1];
  const float* wqkv = (const float*)d_in[2];
  const float* bqkv = (const float*)d_in[3];
  const float* outw = (const float*)d_in[4];
  const float* outb = (const float*)d_in[5];

  char* ws = (char*)d_ws;
  size_t off = 0;
  auto alloc = [&](size_t bytes)->void*{
    void* p = ws + off; off += (bytes + 255) & ~(size_t)255; return p;
  };
  unsigned short* hid_bf  = (unsigned short*)alloc((size_t)M_TOTAL*HIDDEN*2);   // reused as ctx
  unsigned short* wqkv_bf = (unsigned short*)alloc((size_t)QKV_N*HIDDEN*2);
  unsigned short* outw_bf = (unsigned short*)alloc((size_t)HIDDEN*HIDDEN*2);
  unsigned short* qkv_bf  = (unsigned short*)alloc((size_t)M_TOTAL*QKV_N*2);    // reused as partials
  unsigned short* Qp      = (unsigned short*)alloc((size_t)BATCH*NHEADS*SEQ*QKS*2);
  unsigned short* Kp      = (unsigned short*)alloc((size_t)BATCH*NHEADS*SEQ*QKS*2);
  unsigned short* Vt      = (unsigned short*)alloc((size_t)BATCH*NHEADS*HEAD*SEQ*2);
  if (off > ws_size) return;

  unsigned short* pO  = qkv_bf;                                            // 47.2 MB
  float*          pML = (float*)(qkv_bf + (size_t)64*PART_SLOTS*128*HEAD); // 2.36 MB

  convert_f32_bf16<<<dim3(1024), dim3(256), 0, stream>>>(hid,  hid_bf,  M_TOTAL*HIDDEN/4);
  convert_f32_bf16<<<dim3(2048), dim3(256), 0, stream>>>(wqkv, wqkv_bf, QKV_N*HIDDEN/4);
  convert_f32_bf16<<<dim3(1024), dim3(256), 0, stream>>>(outw, outw_bf, HIDDEN*HIDDEN/4);

  gemm256<true><<<dim3(QKV_N/256, M_TOTAL/256), dim3(512), 0, stream>>>(
      hid_bf, wqkv_bf, bqkv, (void*)qkv_bf, M_TOTAL, QKV_N, HIDDEN);

  rope_scatter<<<dim3(BATCH*NHEADS*16), dim3(256), 0, stream>>>(qkv_bf, pos, Qp, Kp, Vt);

  unsigned short* ctx = hid_bf;  // hidden_bf dead after QKV GEMM
  attn_fd<<<dim3(2560), dim3(256), 0, stream>>>(Qp, Kp, Vt, ctx, pO, pML);
  attn_combine<<<dim3(64*12), dim3(256), 0, stream>>>(pO, pML, ctx);

  gemm256<false><<<dim3(HIDDEN/256, M_TOTAL/256), dim3(512), 0, stream>>>(
      ctx, outw_bf, outb, d_out, M_TOTAL, HIDDEN, HIDDEN);
}

// Round 17
// 462.084 us; speedup vs baseline: 1.2278x; 1.0258x over previous
//
#include <hip/hip_runtime.h>
#include <stdint.h>

#define HIDDEN  2560
#define NHEADS  32
#define HEAD    80
#define QKS     96           // Q/K padded head stride (3 x 32 for MFMA K)
#define SEQ     2048
#define BATCH   2
#define M_TOTAL (BATCH*SEQ)  // 4096
#define QKV_N   (3*HIDDEN)   // 7680
#define PART_SLOTS 36

typedef __attribute__((ext_vector_type(8))) short  short8;
typedef __attribute__((ext_vector_type(4))) float  floatx4;
typedef __attribute__((ext_vector_type(4))) float  fvec4;
typedef __attribute__((ext_vector_type(4))) unsigned short usvec4;
typedef __attribute__((ext_vector_type(2))) unsigned int uint2v;

#define SBAR() __builtin_amdgcn_sched_barrier(0)

__device__ __forceinline__ unsigned short f2bf(float x){
  union { float f; unsigned u; } v; v.f = x;
  unsigned r = v.u + 0x7fffu + ((v.u >> 16) & 1u);
  return (unsigned short)(r >> 16);
}
__device__ __forceinline__ float bf2f(unsigned short h){
  union { unsigned u; float f; } v; v.u = ((unsigned)h) << 16;
  return v.f;
}
__device__ __forceinline__ unsigned cvt_pk_bf16(float lo, float hi){
  unsigned r;
  asm volatile("v_cvt_pk_bf16_f32 %0, %1, %2" : "=v"(r) : "v"(lo), "v"(hi));
  return r;
}
__device__ __forceinline__ void gload16(const void* g, void* l){
  __builtin_amdgcn_global_load_lds(
    (const __attribute__((address_space(1))) void*)g,
    (__attribute__((address_space(3))) void*)l, 16, 0, 0);
}

// ---------------- fused f32 -> bf16 converts (one launch) ----------------
__global__ __launch_bounds__(256)
void convert3(const float* __restrict__ s0, unsigned short* __restrict__ d0, int n0,
              const float* __restrict__ s1, unsigned short* __restrict__ d1, int n1,
              const float* __restrict__ s2, unsigned short* __restrict__ d2, int n2)
{
  const int idx = blockIdx.x*blockDim.x + threadIdx.x;
  const int stride = gridDim.x*blockDim.x;
  for (int i = idx; i < n0; i += stride){
    fvec4 v = *(const fvec4*)(s0 + (size_t)i*4);
    usvec4 o; o[0]=f2bf(v[0]); o[1]=f2bf(v[1]); o[2]=f2bf(v[2]); o[3]=f2bf(v[3]);
    *(usvec4*)(d0 + (size_t)i*4) = o;
  }
  for (int i = idx; i < n1; i += stride){
    fvec4 v = *(const fvec4*)(s1 + (size_t)i*4);
    usvec4 o; o[0]=f2bf(v[0]); o[1]=f2bf(v[1]); o[2]=f2bf(v[2]); o[3]=f2bf(v[3]);
    *(usvec4*)(d1 + (size_t)i*4) = o;
  }
  for (int i = idx; i < n2; i += stride){
    fvec4 v = *(const fvec4*)(s2 + (size_t)i*4);
    usvec4 o; o[0]=f2bf(v[0]); o[1]=f2bf(v[1]); o[2]=f2bf(v[2]); o[3]=f2bf(v[3]);
    *(usvec4*)(d2 + (size_t)i*4) = o;
  }
}

// ---------------- 256x256 GEMM, counted-vmcnt (r11 config, QKV) ----------
// Square XCD band swizzle: 8 XCDs as 2(n) x 4(m) bands; requires gx%2==0,
// gy%4==0, nwg%8==0 (QKV: 30x16 -> bands 15x4).
template<bool OUT_BF16>
__global__ __launch_bounds__(512, 2)
void gemm256(const unsigned short* __restrict__ A, const unsigned short* __restrict__ Bm,
             const float* __restrict__ bias, void* __restrict__ Cout,
             int M, int N, int K)
{
  __shared__ __align__(16) unsigned short lds[65536];   // 128 KB
  const int tid  = threadIdx.x;
  const int lane = tid & 63;
  const int w    = tid >> 6;          // wave 0..7
  const int wm   = w >> 2;            // 0..1
  const int wn   = w & 3;             // 0..3
  const int l15  = lane & 15, lg = lane >> 4;

  // square XCD band swizzle
  const int gx  = gridDim.x;
  const int lid = blockIdx.y*gx + blockIdx.x;
  const int xcd = lid & 7, jj = lid >> 3;
  const int bw  = gx >> 1;                 // n-band width
  const int bh2 = gridDim.y >> 2;          // m-band height
  const int bx  = (xcd & 1)*bw  + jj % bw;
  const int by  = (xcd >> 1)*bh2 + jj / bw;
  const int bn0 = bx * 256;
  const int bm0 = by * 256;

  const int nt = K >> 6;              // K-tiles of 64

  int rowq[2], cq[2];
  #pragma unroll
  for (int q=0;q<2;q++){
    int u = (w*2+q)*64 + lane;
    rowq[q] = u >> 2;
    cq[q]   = ((u & 3) - (rowq[q] >> 1)) & 3;
  }
  const int rot = (lg + (l15 >> 1)) & 3;   // read-side chunk rotation

  floatx4 acc[8][4];
  #pragma unroll
  for (int m=0;m<8;m++)
    #pragma unroll
    for (int n=0;n<4;n++) acc[m][n] = (floatx4)0.0f;

  auto STAGE = [&](int tau, int kkh){
    const int bufb = tau & 1;
    const size_t kofs = (size_t)tau*64 + kkh*32;
    const unsigned sA = (unsigned)(((bufb*2 + 0)*2 + kkh) * 8192);
    const unsigned sB = (unsigned)(((bufb*2 + 1)*2 + kkh) * 8192);
    #pragma unroll
    for (int q=0;q<2;q++){
      gload16(A  + (size_t)(bm0 + rowq[q])*K + kofs + cq[q]*8, &lds[sA + (w*2+q)*512]);
      gload16(Bm + (size_t)(bn0 + rowq[q])*K + kofs + cq[q]*8, &lds[sB + (w*2+q)*512]);
    }
  };
  auto COMPUTE = [&](int bufb, int kkh){
    const unsigned short* As = &lds[((bufb*2+0)*2+kkh)*8192];
    const unsigned short* Bs = &lds[((bufb*2+1)*2+kkh)*8192];
    short8 af[8], bfv[4];
    __builtin_amdgcn_s_setprio(1);
    #pragma unroll
    for (int n=0;n<4;n++)
      bfv[n] = *(const short8*)&Bs[(((wn*64 + n*16 + l15)<<2) + rot)*8];
    #pragma unroll
    for (int m=0;m<8;m++)
      af[m] = *(const short8*)&As[(((wm*128 + m*16 + l15)<<2) + rot)*8];
    #pragma unroll
    for (int m=0;m<8;m++)
      #pragma unroll
      for (int n=0;n<4;n++)
        acc[m][n] = __builtin_amdgcn_mfma_f32_16x16x32_bf16(af[m], bfv[n], acc[m][n], 0, 0, 0);
    __builtin_amdgcn_s_setprio(0);
  };

  // prologue: issue (0,kk0),(0,kk1),(1,kk0); oldest group landed at vmcnt(8)
  STAGE(0,0);
  STAGE(0,1);
  STAGE(1,0);
  asm volatile("s_waitcnt vmcnt(8)" ::: "memory");
  __builtin_amdgcn_s_barrier(); SBAR();

  for (int t=0; t<nt; ++t){
    const int c = t & 1;
    if (t+1 < nt) STAGE(t+1, 1);
    COMPUTE(c, 0);
    if (t+1 < nt) asm volatile("s_waitcnt vmcnt(8)" ::: "memory");
    else          asm volatile("s_waitcnt vmcnt(0)" ::: "memory");
    __builtin_amdgcn_s_barrier(); SBAR();
    if (t+2 < nt) STAGE(t+2, 0);
    COMPUTE(c, 1);
    if (t+1 < nt){
      if (t+2 < nt) asm volatile("s_waitcnt vmcnt(8)" ::: "memory");
      else          asm volatile("s_waitcnt vmcnt(4)" ::: "memory");
      __builtin_amdgcn_s_barrier(); SBAR();
    }
  }

  // epilogue
  #pragma unroll
  for (int m=0;m<8;m++){
    #pragma unroll
    for (int n=0;n<4;n++){
      int col = bn0 + wn*64 + n*16 + l15;
      float bs = bias[col];
      #pragma unroll
      for (int r=0;r<4;r++){
        int row = bm0 + wm*128 + m*16 + lg*4 + r;
        float v = acc[m][n][r] + bs;
        if (OUT_BF16) ((unsigned short*)Cout)[(size_t)row*N + col] = f2bf(v);
        else          ((float*)Cout)[(size_t)row*N + col] = v;
      }
    }
  }
}

// ---------------- 128x128 GEMM (r9 config) — for the out-projection -------
// 640 blocks at ~5/CU: cross-block TLP covers stage stalls; better than
// 256^2's 160-block 62%-occupancy run for this shape.
template<bool OUT_BF16>
__global__ __launch_bounds__(256)
void gemm_bt(const unsigned short* __restrict__ A, const unsigned short* __restrict__ Bm,
             const float* __restrict__ bias, void* __restrict__ Cout,
             int M, int N, int K)
{
  __shared__ __align__(16) unsigned short Alds[128*64];
  __shared__ __align__(16) unsigned short Blds[128*64];
  const int tid  = threadIdx.x;
  const int lane = tid & 63;
  const int wid  = tid >> 6;
  const int wr   = wid >> 1, wc = wid & 1;

  const int gx  = gridDim.x;
  const int lid = blockIdx.y*gx + blockIdx.x;
  const int nwg = gx*gridDim.y;
  const int qch = nwg >> 3;
  const int sl  = (lid & 7)*qch + (lid >> 3);
  const int bx  = sl % gx, by = sl / gx;

  const int rowA0 = by * 128;
  const int rowB0 = bx * 128;
  const int l15 = lane & 15, lg = lane >> 4;

  floatx4 acc[4][4];
  #pragma unroll
  for (int i=0;i<4;i++)
    #pragma unroll
    for (int j=0;j<4;j++) acc[i][j] = (floatx4)0.0f;

  int srow[4], scol[4];
  #pragma unroll
  for (int i=0;i<4;i++){
    int c = wid*4 + i;
    int e = c*512 + lane*8;
    int row = e >> 6;
    int col8 = (e >> 3) & 7;
    srow[i] = row;
    scol[i] = ((col8 ^ (row & 7)) << 3);
  }

  for (int k0 = 0; k0 < K; k0 += 64){
    #pragma unroll
    for (int i=0;i<4;i++){
      int c = wid*4 + i;
      gload16(A  + (size_t)(rowA0 + srow[i])*K + k0 + scol[i], &Alds[c*512]);
      gload16(Bm + (size_t)(rowB0 + srow[i])*K + k0 + scol[i], &Blds[c*512]);
    }
    __syncthreads();
    #pragma unroll
    for (int kk = 0; kk < 64; kk += 32){
      short8 af[4], bfv[4];
      #pragma unroll
      for (int mi=0; mi<4; mi++){
        int r = wr*64 + mi*16 + l15;
        int ch = ((kk>>3) + lg) ^ (r & 7);
        af[mi] = *(const short8*)&Alds[r*64 + ch*8];
      }
      #pragma unroll
      for (int ni=0; ni<4; ni++){
        int r = wc*64 + ni*16 + l15;
        int ch = ((kk>>3) + lg) ^ (r & 7);
        bfv[ni] = *(const short8*)&Blds[r*64 + ch*8];
      }
      #pragma unroll
      for (int mi=0; mi<4; mi++)
        #pragma unroll
        for (int ni=0; ni<4; ni++)
          acc[mi][ni] = __builtin_amdgcn_mfma_f32_16x16x32_bf16(af[mi], bfv[ni], acc[mi][ni], 0, 0, 0);
    }
    __syncthreads();
  }

  #pragma unroll
  for (int mi=0; mi<4; mi++){
    #pragma unroll
    for (int ni=0; ni<4; ni++){
      int col = rowB0 + wc*64 + ni*16 + l15;
      float bs = bias[col];
      #pragma unroll
      for (int r=0;r<4;r++){
        int row = rowA0 + wr*64 + mi*16 + lg*4 + r;
        float v = acc[mi][ni][r] + bs;
        if (OUT_BF16) ((unsigned short*)Cout)[(size_t)row*N + col] = f2bf(v);
        else          ((float*)Cout)[(size_t)row*N + col] = v;
      }
    }
  }
}

// ---------------- RoPE + scatter to attention layouts ----------------
// qkv [B,S,7680] bf16 -> Qp,Kp [B,H,S,96] (rope d<32, zero d>=80), Vt [B,H,80,S]
__global__ __launch_bounds__(256)
void rope_scatter(const unsigned short* __restrict__ qkv,
                  const int* __restrict__ pos_ids,
                  unsigned short* __restrict__ Qp, unsigned short* __restrict__ Kp,
                  unsigned short* __restrict__ Vt)
{
  __shared__ float cosb[128*16];
  __shared__ float sinb[128*16];
  __shared__ __align__(16) unsigned short vtile[128*88];
  const int tid = threadIdx.x;
  const int blk = blockIdx.x;
  const int st = blk & 15, h = (blk >> 4) & 31, b = blk >> 9;
  const int s0 = st*128;

  for (int idx = tid; idx < 128*16; idx += 256){
    int sl = idx >> 4, i = idx & 15;
    float p = (float)pos_ids[b*SEQ + s0 + sl];
    float inv = exp2f(-(float)i * (13.287712379549449f/16.0f));
    float ang = p * inv;
    cosb[idx] = cosf(ang);
    sinb[idx] = sinf(ang);
  }
  __syncthreads();

  const size_t qkrow = (size_t)(b*SEQ + s0)*QKV_N;
  const size_t obase = ((size_t)(b*NHEADS + h)*SEQ + s0)*QKS;
  #pragma unroll
  for (int part = 0; part < 2; part++){
    const int cbase = part*HIDDEN + h*HEAD;
    unsigned short* outp = part ? Kp : Qp;
    for (int idx = tid; idx < 128*QKS; idx += 256){
      int sl = idx / QKS, d = idx - sl*QKS;
      const size_t rb = qkrow + (size_t)sl*QKV_N + cbase;
      float v;
      if (d < 16){
        float x1 = bf2f(qkv[rb + d]);
        float x2 = bf2f(qkv[rb + d + 16]);
        v = x1*cosb[sl*16 + d] - x2*sinb[sl*16 + d];
      } else if (d < 32){
        int i = d - 16;
        float x1 = bf2f(qkv[rb + d - 16]);
        float x2 = bf2f(qkv[rb + d]);
        v = x2*cosb[sl*16 + i] + x1*sinb[sl*16 + i];
      } else if (d < HEAD){
        v = bf2f(qkv[rb + d]);
      } else v = 0.0f;
      outp[obase + (size_t)sl*QKS + d] = f2bf(v);
    }
  }

  for (int idx = tid; idx < 128*HEAD; idx += 256){
    int sl = idx / HEAD, d = idx - sl*HEAD;
    vtile[sl*88 + d] = qkv[qkrow + (size_t)sl*QKV_N + 2*HIDDEN + h*HEAD + d];
  }
  __syncthreads();
  const size_t vtb = ((size_t)(b*NHEADS + h)*HEAD)*SEQ + s0;
  for (int idx = tid; idx < HEAD*128; idx += 256){
    int d = idx >> 7, sl = idx & 127;
    Vt[vtb + (size_t)d*SEQ + sl] = vtile[sl*88 + d];
  }
}

// ---------------- flash attention (causal, kv-split, double-buffered LDS) --
__global__ __launch_bounds__(256, 4)
void attn_fd(const unsigned short* __restrict__ Qp,
             const unsigned short* __restrict__ Kp,
             const unsigned short* __restrict__ Vt,
             unsigned short* __restrict__ ctx,
             unsigned short* __restrict__ pO,
             float* __restrict__ pML)
{
  __shared__ __align__(16) unsigned short Klds[2][64*96];  // 24 KB, swizzled
  __shared__ __align__(16) unsigned short Vlds[2][80*64];  // 20 KB, swizzled
  __shared__ __align__(16) unsigned short p_lds[4][32*36]; // 9.2 KB
  const int tid = threadIdx.x;
  const int lane = tid & 63, w = tid >> 6;
  const int l15 = lane & 15, lg = lane >> 4;

  const int bid = blockIdx.x;
  const int xcd = bid & 7, j = bid >> 3;     // j 0..319
  const int bh  = (j/40)*8 + xcd;
  const int tr  = j - (j/40)*40;

  int qt, part, np;
  if (tr < 16)      { qt = 12 + (tr>>2); part = tr & 3; np = 4; }
  else if (tr < 28) { int t = tr-16; int q3 = t/3; qt = 8 + q3; part = t - q3*3; np = 3; }
  else if (tr < 36) { int t = tr-28; qt = 4 + (t>>1); part = t & 1; np = 2; }
  else              { qt = tr - 36; part = 0; np = 1; }
  const int nk  = 2*qt + 2;
  const int kt0 = (part*nk)/np, kt1 = ((part+1)*nk)/np;
  const int q0  = qt*128 + w*32;

  const unsigned short* Qb = Qp + ((size_t)bh*SEQ)*QKS;
  const unsigned short* Kb = Kp + ((size_t)bh*SEQ)*QKS;
  const unsigned short* Vb = Vt + ((size_t)bh*HEAD)*SEQ;

  short8 qf[2][3];
  #pragma unroll
  for (int mi=0; mi<2; mi++)
    #pragma unroll
    for (int kc=0; kc<3; kc++)
      qf[mi][kc] = *(const short8*)&Qb[(size_t)(q0 + mi*16 + l15)*QKS + kc*32 + lg*8];

  int ksrow[3], ksc[3];
  #pragma unroll
  for (int t=0;t<3;t++){
    int ci = (w*3 + t)*64 + lane;       // K chunk 0..767
    int row = ci/12, c = ci - row*12;
    ksrow[t] = row;
    ksc[t]   = (c ^ (row & 3))*8;
  }
  int vsrow[3], vsc[3];
  #pragma unroll
  for (int t=0;t<3;t++){
    int i = w + 4*t;                    // V instr 0..9
    int row = i*8 + (lane >> 3), c = lane & 7;
    vsrow[t] = row;
    vsc[t]   = (c ^ (row & 7))*8;
  }

  auto STAGE_T = [&](int kt, int bb){
    #pragma unroll
    for (int t=0;t<3;t++)
      gload16(Kb + (size_t)(kt*64 + ksrow[t])*QKS + ksc[t], &Klds[bb][(w*3+t)*512]);
    #pragma unroll
    for (int t=0;t<3;t++){
      int i = w + 4*t;
      if (i < 10)
        gload16(Vb + (size_t)vsrow[t]*SEQ + kt*64 + vsc[t], &Vlds[bb][i*512]);
    }
  };

  float mrun[2] = {-3e38f, -3e38f};
  float lrun[2] = {0.0f, 0.0f};
  floatx4 oacc[2][5];
  #pragma unroll
  for (int mi=0;mi<2;mi++)
    #pragma unroll
    for (int di=0;di<5;di++) oacc[mi][di] = (floatx4)0.0f;

  const float SC = 0.1118033988749895f * 1.4426950408889634f; // 1/sqrt(80)*log2(e)

  STAGE_T(kt0, 0);
  __syncthreads();

  for (int kt = kt0; kt < kt1; kt++){
    const int cur = (kt - kt0) & 1;
    if (kt+1 < kt1) STAGE_T(kt+1, cur^1);

    if (kt*64 <= q0 + 31){
      floatx4 sacc[2][4];
      #pragma unroll
      for (int mi=0;mi<2;mi++)
        #pragma unroll
        for (int ni=0;ni<4;ni++) sacc[mi][ni] = (floatx4)0.0f;

      __builtin_amdgcn_s_setprio(1);
      #pragma unroll
      for (int kc=0; kc<3; kc++){
        short8 kf[4];
        #pragma unroll
        for (int ni=0; ni<4; ni++){
          int r = ni*16 + l15;
          kf[ni] = *(const short8*)&Klds[cur][r*96 + (((kc*4+lg) ^ (r & 3))<<3)];
        }
        #pragma unroll
        for (int mi=0; mi<2; mi++)
          #pragma unroll
          for (int ni=0; ni<4; ni++)
            sacc[mi][ni] = __builtin_amdgcn_mfma_f32_16x16x32_bf16(kf[ni], qf[mi][kc], sacc[mi][ni], 0, 0, 0);
      }
      __builtin_amdgcn_s_setprio(0);

      if (kt*64 + 63 > q0){
        #pragma unroll
        for (int mi=0; mi<2; mi++){
          int qrow = q0 + mi*16 + l15;
          #pragma unroll
          for (int ni=0; ni<4; ni++){
            int kb = kt*64 + ni*16 + lg*4;
            #pragma unroll
            for (int r=0; r<4; r++)
              if (kb + r > qrow) sacc[mi][ni][r] = -3e38f;
          }
        }
      }

      #pragma unroll
      for (int mi=0; mi<2; mi++){
        float pm = -3e38f;
        #pragma unroll
        for (int ni=0; ni<4; ni++)
          #pragma unroll
          for (int r=0; r<4; r++) pm = fmaxf(pm, sacc[mi][ni][r]);
        pm = fmaxf(pm, __shfl_xor(pm, 16));
        pm = fmaxf(pm, __shfl_xor(pm, 32));
        float mold = mrun[mi];
        float mnew = fmaxf(mold, pm);
        float msc  = mnew*SC;
        float alpha = __builtin_amdgcn_exp2f(mold*SC - msc);
        float rs = 0.0f;
        #pragma unroll
        for (int ni=0; ni<4; ni++)
          #pragma unroll
          for (int r=0; r<4; r++){
            float p = __builtin_amdgcn_exp2f(sacc[mi][ni][r]*SC - msc);
            sacc[mi][ni][r] = p;
            rs += p;
          }
        rs += __shfl_xor(rs, 16);
        rs += __shfl_xor(rs, 32);
        lrun[mi] = lrun[mi]*alpha + rs;
        mrun[mi] = mnew;
        #pragma unroll
        for (int di=0; di<5; di++) oacc[mi][di] *= alpha;
      }

      #pragma unroll
      for (int kk=0; kk<2; kk++){
        #pragma unroll
        for (int mi=0; mi<2; mi++)
          #pragma unroll
          for (int nl=0; nl<2; nl++){
            int ni = kk*2 + nl;
            uint2v pk;
            pk[0] = cvt_pk_bf16(sacc[mi][ni][0], sacc[mi][ni][1]);
            pk[1] = cvt_pk_bf16(sacc[mi][ni][2], sacc[mi][ni][3]);
            *(uint2v*)&p_lds[w][(mi*16 + l15)*36 + nl*16 + lg*4] = pk;
          }
        __builtin_amdgcn_s_setprio(1);
        short8 pa[2];
        #pragma unroll
        for (int mi=0;mi<2;mi++)
          pa[mi] = *(const short8*)&p_lds[w][(mi*16 + l15)*36 + lg*8];
        #pragma unroll
        for (int di=0; di<5; di++){
          int r = di*16 + l15;
          short8 vf = *(const short8*)&Vlds[cur][r*64 + (((kk*4+lg) ^ (r & 7))<<3)];
          #pragma unroll
          for (int mi=0;mi<2;mi++)
            oacc[mi][di] = __builtin_amdgcn_mfma_f32_16x16x32_bf16(vf, pa[mi], oacc[mi][di], 0, 0, 0);
        }
        __builtin_amdgcn_s_setprio(0);
      }
    }
    __syncthreads();
  }

  const int b = bh >> 5, h = bh & 31;
  if (np == 1){
    #pragma unroll
    for (int mi=0;mi<2;mi++){
      float inv = 1.0f/lrun[mi];
      size_t crow = ((size_t)(b*SEQ + q0 + mi*16 + l15))*HIDDEN + h*HEAD;
      #pragma unroll
      for (int di=0;di<5;di++){
        uint2v pk;
        pk[0] = cvt_pk_bf16(oacc[mi][di][0]*inv, oacc[mi][di][1]*inv);
        pk[1] = cvt_pk_bf16(oacc[mi][di][2]*inv, oacc[mi][di][3]*inv);
        *(uint2v*)&ctx[crow + di*16 + lg*4] = pk;
      }
    }
  } else {
    int base;
    if (np == 2)      base = (qt-4)*2;
    else if (np == 3) base = 8 + (qt-8)*3;
    else              base = 20 + (qt-12)*4;
    const int pslot = bh*PART_SLOTS + base + part;
    unsigned short* Ob = pO + (size_t)pslot*128*HEAD;
    #pragma unroll
    for (int mi=0;mi<2;mi++){
      int grow = w*32 + mi*16 + l15;
      #pragma unroll
      for (int di=0;di<5;di++){
        uint2v pk;
        pk[0] = cvt_pk_bf16(oacc[mi][di][0], oacc[mi][di][1]);
        pk[1] = cvt_pk_bf16(oacc[mi][di][2], oacc[mi][di][3]);
        *(uint2v*)&Ob[grow*HEAD + di*16 + lg*4] = pk;
      }
      if (lg == 0){
        float* mlb = pML + ((size_t)pslot*128 + grow)*2;
        mlb[0] = mrun[mi];
        mlb[1] = lrun[mi];
      }
    }
  }
}

// ---------------- combine partials (coalesced flat-tile reads) ----------------
__global__ __launch_bounds__(256)
void attn_combine(const unsigned short* __restrict__ pO, const float* __restrict__ pML,
                  unsigned short* __restrict__ ctx)
{
  const int bid = blockIdx.x;              // 64*12
  const int bh = bid / 12, qt = 4 + (bid - (bid/12)*12);
  int base, np;
  if (qt < 8)       { base = (qt-4)*2;       np = 2; }
  else if (qt < 12) { base = 8 + (qt-8)*3;   np = 3; }
  else              { base = 20 + (qt-12)*4; np = 4; }
  const int slot0 = bh*PART_SLOTS + base;
  const float SC = 0.1118033988749895f * 1.4426950408889634f;
  const int b = bh >> 5, h = bh & 31;

  #pragma unroll
  for (int c = 0; c < 5; c++){
    const int e   = c*2048 + threadIdx.x*8;   // element in flat 128x80 tile
    const int row = e / 80, d = e - row*80;   // 80%8==0: never crosses rows

    float m[4], l[4], ms = -3e38f;
    for (int p=0;p<np;p++){
      const float* mlb = pML + ((size_t)(slot0+p)*128 + row)*2;
      m[p] = mlb[0]; l[p] = mlb[1];
      ms = fmaxf(ms, m[p]);
    }
    float wgt[4], lsum = 0.0f;
    for (int p=0;p<np;p++){
      wgt[p] = exp2f((m[p]-ms)*SC);
      lsum += wgt[p]*l[p];
    }
    const float inv = 1.0f/lsum;

    float acc[8] = {0,0,0,0,0,0,0,0};
    for (int p=0;p<np;p++){
      short8 v = *(const short8*)&pO[(size_t)(slot0+p)*128*HEAD + e];
      #pragma unroll
      for (int j=0;j<8;j++) acc[j] += wgt[p]*bf2f((unsigned short)v[j]);
    }
    short8 o;
    #pragma unroll
    for (int j=0;j<8;j++) o[j] = (short)f2bf(acc[j]*inv);
    *(short8*)&ctx[((size_t)(b*SEQ + qt*128 + row))*HIDDEN + h*HEAD + d] = o;
  }
}

// ---------------- launch ----------------
extern "C" void kernel_launch(void* const* d_in, const int* in_sizes, int n_in,
                              void* d_out, int out_size, void* d_ws, size_t ws_size,
                              hipStream_t stream)
{
  const int*   pos  = (const int*)  d_in[0];
  const float* hid  = (const float*)d_in[1];
  const float* wqkv = (const float*)d_in[2];
  const float* bqkv = (const float*)d_in[3];
  const float* outw = (const float*)d_in[4];
  const float* outb = (const float*)d_in[5];

  char* ws = (char*)d_ws;
  size_t off = 0;
  auto alloc = [&](size_t bytes)->void*{
    void* p = ws + off; off += (bytes + 255) & ~(size_t)255; return p;
  };
  unsigned short* hid_bf  = (unsigned short*)alloc((size_t)M_TOTAL*HIDDEN*2);   // reused as ctx
  unsigned short* wqkv_bf = (unsigned short*)alloc((size_t)QKV_N*HIDDEN*2);
  unsigned short* outw_bf = (unsigned short*)alloc((size_t)HIDDEN*HIDDEN*2);
  unsigned short* qkv_bf  = (unsigned short*)alloc((size_t)M_TOTAL*QKV_N*2);    // reused as partials
  unsigned short* Qp      = (unsigned short*)alloc((size_t)BATCH*NHEADS*SEQ*QKS*2);
  unsigned short* Kp      = (unsigned short*)alloc((size_t)BATCH*NHEADS*SEQ*QKS*2);
  unsigned short* Vt      = (unsigned short*)alloc((size_t)BATCH*NHEADS*HEAD*SEQ*2);
  if (off > ws_size) return;

  unsigned short* pO  = qkv_bf;                                            // 47.2 MB
  float*          pML = (float*)(qkv_bf + (size_t)64*PART_SLOTS*128*HEAD); // 2.36 MB

  convert3<<<dim3(2048), dim3(256), 0, stream>>>(
      hid,  hid_bf,  M_TOTAL*HIDDEN/4,
      wqkv, wqkv_bf, QKV_N*HIDDEN/4,
      outw, outw_bf, HIDDEN*HIDDEN/4);

  gemm256<true><<<dim3(QKV_N/256, M_TOTAL/256), dim3(512), 0, stream>>>(
      hid_bf, wqkv_bf, bqkv, (void*)qkv_bf, M_TOTAL, QKV_N, HIDDEN);

  rope_scatter<<<dim3(BATCH*NHEADS*16), dim3(256), 0, stream>>>(qkv_bf, pos, Qp, Kp, Vt);

  unsigned short* ctx = hid_bf;  // hidden_bf dead after QKV GEMM
  attn_fd<<<dim3(2560), dim3(256), 0, stream>>>(Qp, Kp, Vt, ctx, pO, pML);
  attn_combine<<<dim3(64*12), dim3(256), 0, stream>>>(pO, pML, ctx);

  gemm_bt<false><<<dim3(HIDDEN/128, M_TOTAL/128), dim3(256), 0, stream>>>(
      ctx, outw_bf, outb, d_out, M_TOTAL, HIDDEN, HIDDEN);
}